// Round 2
// baseline (1009.798 us; speedup 1.0000x reference)
//
#include <hip/hip_runtime.h>

typedef __bf16 bf16x8 __attribute__((ext_vector_type(8)));
typedef float f32x4 __attribute__((ext_vector_type(4)));
typedef unsigned short u16;

__device__ __forceinline__ float b2f(u16 u) {
  union { unsigned int i; float f; } v; v.i = ((unsigned int)u) << 16; return v.f;
}
__device__ __forceinline__ u16 f2b(float f) {
  union { float f; unsigned int i; } v; v.f = f;
  unsigned int x = v.i;
  x += 0x7fffu + ((x >> 16) & 1u);   // round-to-nearest-even
  return (u16)(x >> 16);
}
__device__ __forceinline__ float gelu_f(float x) {
  return 0.5f * x * (1.0f + erff(x * 0.7071067811865476f));
}

union U4 { uint4 u; u16 s[8]; };

// ---------------- fp32 -> bf16 convert (weights) ----------------
__global__ __launch_bounds__(256) void cvt_kernel(const float* __restrict__ in,
                                                  u16* __restrict__ out, int n4) {
  int i = blockIdx.x * 256 + threadIdx.x;
  if (i < n4) {
    float4 f = ((const float4*)in)[i];
    ushort4 o;
    o.x = f2b(f.x); o.y = f2b(f.y); o.z = f2b(f.z); o.w = f2b(f.w);
    ((ushort4*)out)[i] = o;
  }
}

// ---------------- LayerNorm: fp32 in, bf16 out, rows of 1024 ----------------
__global__ __launch_bounds__(256) void ln_kernel(const float* __restrict__ x,
    const float* __restrict__ w, const float* __restrict__ b, u16* __restrict__ out) {
  int row = blockIdx.x;
  const float* xr = x + (size_t)row * 1024;
  u16* orow = out + (size_t)row * 1024;
  int tid = threadIdx.x;
  float vals[4];
  float s = 0.f, s2 = 0.f;
  #pragma unroll
  for (int i = 0; i < 4; ++i) {
    float v = xr[tid + 256 * i];
    vals[i] = v; s += v; s2 += v * v;
  }
  __shared__ float rs_[256], rs2_[256];
  rs_[tid] = s; rs2_[tid] = s2;
  __syncthreads();
  for (int st = 128; st > 0; st >>= 1) {
    if (tid < st) { rs_[tid] += rs_[tid + st]; rs2_[tid] += rs2_[tid + st]; }
    __syncthreads();
  }
  float mu = rs_[0] * (1.0f / 1024.0f);
  float var = rs2_[0] * (1.0f / 1024.0f) - mu * mu;
  float inv = rsqrtf(var + 1e-5f);
  #pragma unroll
  for (int i = 0; i < 4; ++i) {
    int c = tid + 256 * i;
    orow[c] = f2b((vals[i] - mu) * inv * w[c] + b[c]);
  }
}

// ---------------- GEMM: C[M,N] = epilogue(A[M,K] * op(B)) ----------------
// BT=false: B is [N,K] (K-major)  -> C = A * B^T      (key matrices)
// BT=true : B is [K,N] (N-major)  -> C = A * B        (val matrices)
// OUTF32: C is float*, res (fp32) added; else C is bf16 (u16*), res ignored.
template <bool BT, bool OUTF32>
__global__ __launch_bounds__(256) void gemm_kernel(
    const u16* __restrict__ A, const u16* __restrict__ B, void* __restrict__ C,
    int M, int N, int K, float alpha, int do_gelu, const float* __restrict__ res) {
  __shared__ __align__(16) u16 As[128][40];  // +8 pad: 2-way LDS banks (free)
  __shared__ __align__(16) u16 Bs[128][40];
  int bn = blockIdx.x, bm = blockIdx.y;
  int tid = threadIdx.x;
  int lane = tid & 63, wv = tid >> 6;
  int wm = wv >> 1, wn = wv & 1;
  int quad = lane >> 4, l16 = lane & 15;
  f32x4 zero = {0.f, 0.f, 0.f, 0.f};
  f32x4 acc[4][4];
  #pragma unroll
  for (int i = 0; i < 4; ++i)
    #pragma unroll
    for (int j = 0; j < 4; ++j) acc[i][j] = zero;
  const u16* Ab = A + (size_t)bm * 128 * K;
  for (int k0 = 0; k0 < K; k0 += 32) {
    #pragma unroll
    for (int i = 0; i < 2; ++i) {          // stage A 128x32
      int l = tid + 256 * i;
      int r = l >> 2, cv = l & 3;
      *(uint4*)&As[r][cv * 8] = *(const uint4*)(Ab + (size_t)r * K + k0 + cv * 8);
    }
    if (!BT) {
      const u16* Bb = B + (size_t)bn * 128 * K;
      #pragma unroll
      for (int i = 0; i < 2; ++i) {        // stage B 128x32 (K-major)
        int l = tid + 256 * i;
        int r = l >> 2, cv = l & 3;
        *(uint4*)&Bs[r][cv * 8] = *(const uint4*)(Bb + (size_t)r * K + k0 + cv * 8);
      }
    } else {
      #pragma unroll
      for (int i = 0; i < 2; ++i) {        // stage B 32x128 (N-major), transpose into LDS
        int l = tid + 256 * i;
        int kr = l >> 4, cv = l & 15;
        U4 u; u.u = *(const uint4*)(B + (size_t)(k0 + kr) * N + (size_t)bn * 128 + cv * 8);
        #pragma unroll
        for (int j = 0; j < 8; ++j) Bs[cv * 8 + j][kr] = u.s[j];
      }
    }
    __syncthreads();
    bf16x8 af[4], bfr[4];
    #pragma unroll
    for (int i = 0; i < 4; ++i)
      af[i] = *(const bf16x8*)&As[wm * 64 + i * 16 + l16][quad * 8];
    #pragma unroll
    for (int j = 0; j < 4; ++j)
      bfr[j] = *(const bf16x8*)&Bs[wn * 64 + j * 16 + l16][quad * 8];
    #pragma unroll
    for (int i = 0; i < 4; ++i)
      #pragma unroll
      for (int j = 0; j < 4; ++j)
        acc[i][j] = __builtin_amdgcn_mfma_f32_16x16x32_bf16(af[i], bfr[j], acc[i][j], 0, 0, 0);
    __syncthreads();
  }
  // epilogue: C/D layout col = lane&15, row = quad*4 + reg (verified m89/m91)
  #pragma unroll
  for (int i = 0; i < 4; ++i) {
    int rbase = bm * 128 + wm * 64 + i * 16 + quad * 4;
    #pragma unroll
    for (int j = 0; j < 4; ++j) {
      int c = bn * 128 + wn * 64 + j * 16 + l16;
      #pragma unroll
      for (int reg = 0; reg < 4; ++reg) {
        float v = acc[i][j][reg] * alpha;
        if (do_gelu) v = gelu_f(v);
        size_t idx = (size_t)(rbase + reg) * N + c;
        if (OUTF32) {
          if (res) v += res[idx];
          ((float*)C)[idx] = v;
        } else {
          ((u16*)C)[idx] = f2b(v);
        }
      }
    }
  }
}

// ---------------- row-wise L2 normalize (in place, bf16): g *= sqrt(P)/||g|| ----------------
__global__ __launch_bounds__(256) void rownorm_kernel(u16* __restrict__ g, int P, float sqrtP) {
  int row = blockIdx.x;
  u16* gr = g + (size_t)row * P;
  int tid = threadIdx.x;
  int nchunk = P >> 3;
  float ss = 0.f;
  for (int c = tid; c < nchunk; c += 256) {
    U4 u; u.u = *(const uint4*)(gr + c * 8);
    #pragma unroll
    for (int j = 0; j < 8; ++j) { float v = b2f(u.s[j]); ss += v * v; }
  }
  __shared__ float red[256];
  red[tid] = ss;
  __syncthreads();
  for (int st = 128; st > 0; st >>= 1) {
    if (tid < st) red[tid] += red[tid + st];
    __syncthreads();
  }
  float scale = sqrtP * rsqrtf(red[0]);
  for (int c = tid; c < nchunk; c += 256) {
    U4 u; u.u = *(const uint4*)(gr + c * 8);
    #pragma unroll
    for (int j = 0; j < 8; ++j) u.s[j] = f2b(b2f(u.s[j]) * scale);
    *(uint4*)(gr + c * 8) = u.u;
  }
}

// ---------------- rotary (in place, bf16) on first 16 dims of each head ----------------
__global__ __launch_bounds__(256) void rotary_kernel(u16* __restrict__ qb, u16* __restrict__ kb) {
  int t = blockIdx.x * 256 + threadIdx.x;  // 0..65535 = (B*S rows)*(NH)
  int m = t >> 4;
  int h = t & 15;
  int s = m & 2047;
  u16* qp = qb + (size_t)m * 1024 + h * 64;
  u16* kp = kb + (size_t)m * 1024 + h * 64;
  float q[16], k[16];
  #pragma unroll
  for (int d = 0; d < 16; ++d) { q[d] = b2f(qp[d]); k[d] = b2f(kp[d]); }
  #pragma unroll
  for (int i = 0; i < 8; ++i) {
    float invf = powf(10000.0f, -(float)i * 0.125f);
    float ang = (float)s * invf;
    float c = cosf(ang), sn = sinf(ang);
    qp[i]     = f2b(q[i] * c - q[i + 8] * sn);
    qp[i + 8] = f2b(q[i + 8] * c + q[i] * sn);
    kp[i]     = f2b(k[i] * c - k[i + 8] * sn);
    kp[i + 8] = f2b(k[i + 8] * c + k[i] * sn);
  }
}

// ---------------- fused causal attention + gelu_l2_norm over keys ----------------
// gelu_l2_norm is a linear per-row rescale -> accumulate unnormalized O and sum(g^2),
// scale at the end by sqrt(2048)/||g||. Masked entries are exact zeros
// (ref: gelu(score-10000) underflows to 0 in fp32).
__global__ __launch_bounds__(256) void attn_kernel(
    const u16* __restrict__ qb, const u16* __restrict__ kb,
    const u16* __restrict__ vb, u16* __restrict__ ob) {
  __shared__ __align__(16) u16 Qs[64][72];
  __shared__ __align__(16) u16 Ks[64][72];
  __shared__ __align__(16) u16 Vts[64][72];  // transposed V: Vts[d][k]
  __shared__ __align__(16) u16 Sg[64][72];   // gelu'd scores (bf16)
  __shared__ float ssq[64][4];
  __shared__ float rowscale[64];
  int bh = blockIdx.x, qt = blockIdx.y;
  int b = bh >> 4, h = bh & 15;
  size_t base = (size_t)b * 2048 * 1024 + (size_t)h * 64;
  const u16* qp = qb + base;
  const u16* kp = kb + base;
  const u16* vp = vb + base;
  int tid = threadIdx.x, lane = tid & 63, wv = tid >> 6;
  int quad = lane >> 4, l16 = lane & 15;
  #pragma unroll
  for (int i = 0; i < 2; ++i) {              // stage Q tile once
    int l = tid + 256 * i;
    int r = l >> 3, cv = l & 7;
    *(uint4*)&Qs[r][cv * 8] = *(const uint4*)(qp + (size_t)(qt * 64 + r) * 1024 + cv * 8);
  }
  ssq[tid >> 2][tid & 3] = 0.f;
  f32x4 zero = {0.f, 0.f, 0.f, 0.f};
  f32x4 oacc[4];
  #pragma unroll
  for (int i = 0; i < 4; ++i) oacc[i] = zero;
  for (int kt = 0; kt <= qt; ++kt) {
    #pragma unroll
    for (int i = 0; i < 2; ++i) {            // stage K tile + V transposed
      int l = tid + 256 * i;
      int r = l >> 3, cv = l & 7;
      *(uint4*)&Ks[r][cv * 8] = *(const uint4*)(kp + (size_t)(kt * 64 + r) * 1024 + cv * 8);
      U4 u; u.u = *(const uint4*)(vp + (size_t)(kt * 64 + r) * 1024 + cv * 8);
      #pragma unroll
      for (int j = 0; j < 8; ++j) Vts[cv * 8 + j][r] = u.s[j];
    }
    __syncthreads();
    // S = Q K^T / 8, mask, gelu -> Sg (each wave: 16 q-rows x 64 k-cols)
    bf16x8 a0 = *(const bf16x8*)&Qs[wv * 16 + l16][quad * 8];
    bf16x8 a1 = *(const bf16x8*)&Qs[wv * 16 + l16][32 + quad * 8];
    #pragma unroll
    for (int sn = 0; sn < 4; ++sn) {
      bf16x8 b0 = *(const bf16x8*)&Ks[sn * 16 + l16][quad * 8];
      bf16x8 b1 = *(const bf16x8*)&Ks[sn * 16 + l16][32 + quad * 8];
      f32x4 sacc = zero;
      sacc = __builtin_amdgcn_mfma_f32_16x16x32_bf16(a0, b0, sacc, 0, 0, 0);
      sacc = __builtin_amdgcn_mfma_f32_16x16x32_bf16(a1, b1, sacc, 0, 0, 0);
      int kidx = kt * 64 + sn * 16 + l16;
      int qbase_ = qt * 64 + wv * 16 + quad * 4;
      #pragma unroll
      for (int reg = 0; reg < 4; ++reg) {
        float xv = sacc[reg] * 0.125f;
        float gl = (kidx <= qbase_ + reg) ? gelu_f(xv) : 0.f;
        Sg[wv * 16 + quad * 4 + reg][sn * 16 + l16] = f2b(gl);
      }
    }
    __syncthreads();
    // per-row sum of squares accumulation (each thread owns (r,qd))
    {
      int r = tid >> 2, qd = tid & 3;
      float s2 = 0.f;
      #pragma unroll
      for (int j = 0; j < 16; ++j) {
        float v = b2f(Sg[r][qd * 16 + j]);
        s2 += v * v;
      }
      ssq[r][qd] += s2;
    }
    // O += g * V
    bf16x8 p0 = *(const bf16x8*)&Sg[wv * 16 + l16][quad * 8];
    bf16x8 p1 = *(const bf16x8*)&Sg[wv * 16 + l16][32 + quad * 8];
    #pragma unroll
    for (int sn = 0; sn < 4; ++sn) {
      bf16x8 v0 = *(const bf16x8*)&Vts[sn * 16 + l16][quad * 8];
      bf16x8 v1 = *(const bf16x8*)&Vts[sn * 16 + l16][32 + quad * 8];
      oacc[sn] = __builtin_amdgcn_mfma_f32_16x16x32_bf16(p0, v0, oacc[sn], 0, 0, 0);
      oacc[sn] = __builtin_amdgcn_mfma_f32_16x16x32_bf16(p1, v1, oacc[sn], 0, 0, 0);
    }
    __syncthreads();
  }
  if (tid < 64)
    rowscale[tid] = sqrtf(2048.0f / (ssq[tid][0] + ssq[tid][1] + ssq[tid][2] + ssq[tid][3]));
  __syncthreads();
  #pragma unroll
  for (int sn = 0; sn < 4; ++sn) {
    #pragma unroll
    for (int reg = 0; reg < 4; ++reg) {
      int r = wv * 16 + quad * 4 + reg;
      int c = sn * 16 + l16;
      float v = oacc[sn][reg] * rowscale[r];
      ob[(size_t)(b * 2048 + qt * 64 + r) * 1024 + h * 64 + c] = f2b(v);
    }
  }
}

extern "C" void kernel_launch(void* const* d_in, const int* in_sizes, int n_in,
                              void* d_out, int out_size, void* d_ws, size_t ws_size,
                              hipStream_t stream) {
  const float* x    = (const float*)d_in[0];
  const float* ln1w = (const float*)d_in[1];
  const float* ln1b = (const float*)d_in[2];
  const float* ln2w = (const float*)d_in[3];
  const float* ln2b = (const float*)d_in[4];
  const float* qk   = (const float*)d_in[5];
  const float* qv   = (const float*)d_in[6];
  const float* kk   = (const float*)d_in[7];
  const float* kv   = (const float*)d_in[8];
  const float* vk   = (const float*)d_in[9];
  const float* vv   = (const float*)d_in[10];
  const float* pk   = (const float*)d_in[11];
  const float* pv   = (const float*)d_in[12];
  const float* fk   = (const float*)d_in[13];
  const float* fv   = (const float*)d_in[14];
  float* out = (float*)d_out;

  const size_t M1 = 1048576;           // 1M elements
  u16* w = (u16*)d_ws;
  // bf16 weight copies
  u16* wqk = w + 0 * M1;  u16* wqv = w + 1 * M1;
  u16* wkk = w + 2 * M1;  u16* wkv = w + 3 * M1;
  u16* wvk = w + 4 * M1;  u16* wvv = w + 5 * M1;
  u16* wpk = w + 6 * M1;  u16* wpv = w + 7 * M1;
  u16* wfk = w + 8 * M1;                  // 4M elems
  u16* wfv = w + 12 * M1;                 // 4M elems
  // bf16 activations
  u16* xn = w + 16 * M1;                  // 4096x1024
  u16* g  = w + 20 * M1;                  // 4096x4096 slot buffer
  u16* qb = w + 36 * M1;
  u16* kb = w + 40 * M1;
  u16* vb = w + 44 * M1;
  u16* ob = w + 48 * M1;
  float* x1 = (float*)(w + 52 * M1);      // 4096x1024 fp32; total = 120 MB

  dim3 blk(256);
  // weights -> bf16
  cvt_kernel<<<1024, blk, 0, stream>>>(qk, wqk, 262144);
  cvt_kernel<<<1024, blk, 0, stream>>>(qv, wqv, 262144);
  cvt_kernel<<<1024, blk, 0, stream>>>(kk, wkk, 262144);
  cvt_kernel<<<1024, blk, 0, stream>>>(kv, wkv, 262144);
  cvt_kernel<<<1024, blk, 0, stream>>>(vk, wvk, 262144);
  cvt_kernel<<<1024, blk, 0, stream>>>(vv, wvv, 262144);
  cvt_kernel<<<1024, blk, 0, stream>>>(pk, wpk, 262144);
  cvt_kernel<<<1024, blk, 0, stream>>>(pv, wpv, 262144);
  cvt_kernel<<<4096, blk, 0, stream>>>(fk, wfk, 1048576);
  cvt_kernel<<<4096, blk, 0, stream>>>(fv, wfv, 1048576);

  ln_kernel<<<4096, blk, 0, stream>>>(x, ln1w, ln1b, xn);
  // q = pattention(xn, q_key, q_val)
  gemm_kernel<false, false><<<dim3(8, 32), blk, 0, stream>>>(xn, wqk, g, 4096, 1024, 1024, 32.0f, 1, nullptr);
  rownorm_kernel<<<4096, blk, 0, stream>>>(g, 1024, 32.0f);
  gemm_kernel<true, false><<<dim3(8, 32), blk, 0, stream>>>(g, wqv, qb, 4096, 1024, 1024, 1.0f, 0, nullptr);
  // k
  gemm_kernel<false, false><<<dim3(8, 32), blk, 0, stream>>>(xn, wkk, g, 4096, 1024, 1024, 32.0f, 1, nullptr);
  rownorm_kernel<<<4096, blk, 0, stream>>>(g, 1024, 32.0f);
  gemm_kernel<true, false><<<dim3(8, 32), blk, 0, stream>>>(g, wkv, kb, 4096, 1024, 1024, 1.0f, 0, nullptr);
  // v
  gemm_kernel<false, false><<<dim3(8, 32), blk, 0, stream>>>(xn, wvk, g, 4096, 1024, 1024, 32.0f, 1, nullptr);
  rownorm_kernel<<<4096, blk, 0, stream>>>(g, 1024, 32.0f);
  gemm_kernel<true, false><<<dim3(8, 32), blk, 0, stream>>>(g, wvv, vb, 4096, 1024, 1024, 1.0f, 0, nullptr);

  rotary_kernel<<<256, blk, 0, stream>>>(qb, kb);
  attn_kernel<<<dim3(32, 32), blk, 0, stream>>>(qb, kb, vb, ob);

  // x1 = x + pattention(o, proj_key, proj_val)   (fp32 residual + fp32 store)
  gemm_kernel<false, false><<<dim3(8, 32), blk, 0, stream>>>(ob, wpk, g, 4096, 1024, 1024, 32.0f, 1, nullptr);
  rownorm_kernel<<<4096, blk, 0, stream>>>(g, 1024, 32.0f);
  gemm_kernel<true, true><<<dim3(8, 32), blk, 0, stream>>>(g, wpv, x1, 4096, 1024, 1024, 1.0f, 0, x);

  // out = x1 + pattention(ln(x1), ffn_key, ffn_val)
  ln_kernel<<<4096, blk, 0, stream>>>(x1, ln2w, ln2b, xn);
  gemm_kernel<false, false><<<dim3(32, 32), blk, 0, stream>>>(xn, wfk, g, 4096, 4096, 1024, 32.0f, 1, nullptr);
  rownorm_kernel<<<4096, blk, 0, stream>>>(g, 4096, 64.0f);
  gemm_kernel<true, true><<<dim3(8, 32), blk, 0, stream>>>(g, wfv, out, 4096, 1024, 4096, 1.0f, 0, x1);
}

// Round 3
// 659.484 us; speedup vs baseline: 1.5312x; 1.5312x over previous
//
#include <hip/hip_runtime.h>

typedef __bf16 bf16x8 __attribute__((ext_vector_type(8)));
typedef float f32x4 __attribute__((ext_vector_type(4)));
typedef unsigned short u16;

__device__ __forceinline__ float b2f(u16 u) {
  union { unsigned int i; float f; } v; v.i = ((unsigned int)u) << 16; return v.f;
}
__device__ __forceinline__ u16 f2b(float f) {
  union { float f; unsigned int i; } v; v.f = f;
  unsigned int x = v.i;
  x += 0x7fffu + ((x >> 16) & 1u);   // round-to-nearest-even
  return (u16)(x >> 16);
}
__device__ __forceinline__ float gelu_f(float x) {
  return 0.5f * x * (1.0f + erff(x * 0.7071067811865476f));
}
// async global->LDS, 16B per lane; LDS dest = wave-uniform base + lane*16
__device__ __forceinline__ void async16(const u16* g, u16* l) {
  __builtin_amdgcn_global_load_lds(
      (const __attribute__((address_space(1))) void*)g,
      (__attribute__((address_space(3))) void*)l, 16, 0, 0);
}

union U4 { uint4 u; u16 s[8]; };

// ---------------- fp32 -> bf16 convert (plain) ----------------
__global__ __launch_bounds__(256) void cvt_kernel(const float* __restrict__ in,
                                                  u16* __restrict__ out, int n4) {
  int i = blockIdx.x * 256 + threadIdx.x;
  if (i < n4) {
    float4 f = ((const float4*)in)[i];
    ushort4 o;
    o.x = f2b(f.x); o.y = f2b(f.y); o.z = f2b(f.z); o.w = f2b(f.w);
    ((ushort4*)out)[i] = o;
  }
}

// ---------------- fp32 [R,Cn] -> bf16 transposed [Cn,R] ----------------
__global__ __launch_bounds__(256) void cvtT_kernel(const float* __restrict__ in,
                                                   u16* __restrict__ out, int R, int Cn) {
  __shared__ float t[32][33];
  int bc = blockIdx.x, br = blockIdx.y;
  int tid = threadIdx.x;
  int r = tid >> 5, c = tid & 31;
  #pragma unroll
  for (int i = 0; i < 4; ++i)
    t[r + i * 8][c] = in[(size_t)(br * 32 + r + i * 8) * Cn + bc * 32 + c];
  __syncthreads();
  #pragma unroll
  for (int i = 0; i < 4; ++i)
    out[(size_t)(bc * 32 + r + i * 8) * R + br * 32 + c] = f2b(t[c][r + i * 8]);
}

// ---------------- LayerNorm: fp32 in, bf16 out, rows of 1024 ----------------
__global__ __launch_bounds__(256) void ln_kernel(const float* __restrict__ x,
    const float* __restrict__ w, const float* __restrict__ b, u16* __restrict__ out) {
  int row = blockIdx.x;
  const float* xr = x + (size_t)row * 1024;
  u16* orow = out + (size_t)row * 1024;
  int tid = threadIdx.x;
  float vals[4];
  float s = 0.f, s2 = 0.f;
  #pragma unroll
  for (int i = 0; i < 4; ++i) {
    float v = xr[tid + 256 * i];
    vals[i] = v; s += v; s2 += v * v;
  }
  __shared__ float rs_[256], rs2_[256];
  rs_[tid] = s; rs2_[tid] = s2;
  __syncthreads();
  for (int st = 128; st > 0; st >>= 1) {
    if (tid < st) { rs_[tid] += rs_[tid + st]; rs2_[tid] += rs2_[tid + st]; }
    __syncthreads();
  }
  float mu = rs_[0] * (1.0f / 1024.0f);
  float var = rs2_[0] * (1.0f / 1024.0f) - mu * mu;
  float inv = rsqrtf(var + 1e-5f);
  #pragma unroll
  for (int i = 0; i < 4; ++i) {
    int c = tid + 256 * i;
    orow[c] = f2b((vals[i] - mu) * inv * w[c] + b[c]);
  }
}

// ---------------- NT GEMM, m97 structure: C[.,N] = epi(A[.,K] * B[N,K]^T) ----------------
// TM in {64,128}; TN fixed 128. 256 threads, 4 waves.
// z-batched via blockIdx.z with element strides sAz/sBz/sCz.
// Staging: global_load_lds width=16 into contiguous LDS (no padding).
template <int TM, bool OUTF32>
__global__ __launch_bounds__(256) void gemm_nt(
    const u16* __restrict__ A, size_t sAz,
    const u16* __restrict__ B, size_t sBz,
    void* __restrict__ C, size_t sCz,
    int N, int K, float alpha, int do_gelu, const float* __restrict__ res) {
  constexpr int AI = TM / 32;                 // a-frags per wave
  __shared__ __align__(16) u16 As[TM * 32];
  __shared__ __align__(16) u16 Bs[128 * 32];
  int bn = blockIdx.x, bm = blockIdx.y, bz = blockIdx.z;
  const u16* Ab = A + (size_t)bz * sAz + (size_t)bm * TM * K;
  const u16* Bb = B + (size_t)bz * sBz + (size_t)bn * 128 * K;
  int tid = threadIdx.x, lane = tid & 63, wv = tid >> 6;
  int quad = lane >> 4, l16 = lane & 15;
  int lr = lane >> 2, lc = (lane & 3) * 8;    // lane's slot within a 16-row issue
  int wm = wv >> 1, wn = wv & 1;
  int RB = wm * (TM / 2);                     // wave row base
  int CB = wn * 64;                           // wave col base
  f32x4 zero = {0.f, 0.f, 0.f, 0.f};
  f32x4 acc[AI][4];
  #pragma unroll
  for (int i = 0; i < AI; ++i)
    #pragma unroll
    for (int j = 0; j < 4; ++j) acc[i][j] = zero;
  for (int k0 = 0; k0 < K; k0 += 32) {
    #pragma unroll
    for (int t = 0; t < TM / 64; ++t) {       // A: TM/16 issues total
      int ia = wv * (TM / 64) + t;
      async16(Ab + (size_t)(ia * 16 + lr) * K + k0 + lc, &As[ia * 512]);
    }
    #pragma unroll
    for (int t = 0; t < 2; ++t) {             // B: 8 issues total
      int ib = wv * 2 + t;
      async16(Bb + (size_t)(ib * 16 + lr) * K + k0 + lc, &Bs[ib * 512]);
    }
    __syncthreads();
    bf16x8 af[AI], bf[4];
    #pragma unroll
    for (int i = 0; i < AI; ++i)
      af[i] = *(const bf16x8*)&As[(RB + i * 16 + l16) * 32 + quad * 8];
    #pragma unroll
    for (int j = 0; j < 4; ++j)
      bf[j] = *(const bf16x8*)&Bs[(CB + j * 16 + l16) * 32 + quad * 8];
    #pragma unroll
    for (int i = 0; i < AI; ++i)
      #pragma unroll
      for (int j = 0; j < 4; ++j)
        acc[i][j] = __builtin_amdgcn_mfma_f32_16x16x32_bf16(af[i], bf[j], acc[i][j], 0, 0, 0);
    __syncthreads();
  }
  // epilogue: C/D layout col = lane&15, row = quad*4 + reg
  #pragma unroll
  for (int i = 0; i < AI; ++i) {
    int rbase = bm * TM + RB + i * 16 + quad * 4;
    #pragma unroll
    for (int j = 0; j < 4; ++j) {
      int c = bn * 128 + CB + j * 16 + l16;
      #pragma unroll
      for (int reg = 0; reg < 4; ++reg) {
        float v = acc[i][j][reg] * alpha;
        if (do_gelu) v = gelu_f(v);
        size_t idx = (size_t)(rbase + reg) * N + c;
        if (OUTF32) {
          if (res) v += res[idx];
          ((float*)C)[idx] = v;
        } else {
          ((u16*)C)[(size_t)bz * sCz + idx] = f2b(v);
        }
      }
    }
  }
}

// ---------------- row-wise L2 normalize (in place, bf16): g *= sqrt(P)/||g|| ----------------
__global__ __launch_bounds__(256) void rownorm_kernel(u16* __restrict__ g, int P, float sqrtP) {
  int row = blockIdx.x;
  u16* gr = g + (size_t)row * P;
  int tid = threadIdx.x;
  int nchunk = P >> 3;
  float ss = 0.f;
  for (int c = tid; c < nchunk; c += 256) {
    U4 u; u.u = *(const uint4*)(gr + c * 8);
    #pragma unroll
    for (int j = 0; j < 8; ++j) { float v = b2f(u.s[j]); ss += v * v; }
  }
  __shared__ float red[256];
  red[tid] = ss;
  __syncthreads();
  for (int st = 128; st > 0; st >>= 1) {
    if (tid < st) red[tid] += red[tid + st];
    __syncthreads();
  }
  float scale = sqrtP * rsqrtf(red[0]);
  for (int c = tid; c < nchunk; c += 256) {
    U4 u; u.u = *(const uint4*)(gr + c * 8);
    #pragma unroll
    for (int j = 0; j < 8; ++j) u.s[j] = f2b(b2f(u.s[j]) * scale);
    *(uint4*)(gr + c * 8) = u.u;
  }
}

// ---------------- rotary (in place, bf16) on first 16 dims of each head ----------------
__global__ __launch_bounds__(256) void rotary_kernel(u16* __restrict__ qb, u16* __restrict__ kb) {
  int t = blockIdx.x * 256 + threadIdx.x;
  int m = t >> 4;
  int h = t & 15;
  int s = m & 2047;
  u16* qp = qb + (size_t)m * 1024 + h * 64;
  u16* kp = kb + (size_t)m * 1024 + h * 64;
  float q[16], k[16];
  #pragma unroll
  for (int d = 0; d < 16; ++d) { q[d] = b2f(qp[d]); k[d] = b2f(kp[d]); }
  #pragma unroll
  for (int i = 0; i < 8; ++i) {
    float invf = powf(10000.0f, -(float)i * 0.125f);
    float ang = (float)s * invf;
    float c = cosf(ang), sn = sinf(ang);
    qp[i]     = f2b(q[i] * c - q[i + 8] * sn);
    qp[i + 8] = f2b(q[i + 8] * c + q[i] * sn);
    kp[i]     = f2b(k[i] * c - k[i + 8] * sn);
    kp[i + 8] = f2b(k[i + 8] * c + k[i] * sn);
  }
}

// ---------------- fused causal attention + gelu_l2_norm over keys ----------------
__global__ __launch_bounds__(256) void attn_kernel(
    const u16* __restrict__ qb, const u16* __restrict__ kb,
    const u16* __restrict__ vb, u16* __restrict__ ob) {
  __shared__ __align__(16) u16 Qs[64][72];
  __shared__ __align__(16) u16 Ks[64][72];
  __shared__ __align__(16) u16 Vts[64][72];
  __shared__ __align__(16) u16 Sg[64][72];
  __shared__ float ssq[64][4];
  __shared__ float rowscale[64];
  int bh = blockIdx.x, qt = blockIdx.y;
  int b = bh >> 4, h = bh & 15;
  size_t base = (size_t)b * 2048 * 1024 + (size_t)h * 64;
  const u16* qp = qb + base;
  const u16* kp = kb + base;
  const u16* vp = vb + base;
  int tid = threadIdx.x, lane = tid & 63, wv = tid >> 6;
  int quad = lane >> 4, l16 = lane & 15;
  #pragma unroll
  for (int i = 0; i < 2; ++i) {
    int l = tid + 256 * i;
    int r = l >> 3, cv = l & 7;
    *(uint4*)&Qs[r][cv * 8] = *(const uint4*)(qp + (size_t)(qt * 64 + r) * 1024 + cv * 8);
  }
  ssq[tid >> 2][tid & 3] = 0.f;
  f32x4 zero = {0.f, 0.f, 0.f, 0.f};
  f32x4 oacc[4];
  #pragma unroll
  for (int i = 0; i < 4; ++i) oacc[i] = zero;
  for (int kt = 0; kt <= qt; ++kt) {
    #pragma unroll
    for (int i = 0; i < 2; ++i) {
      int l = tid + 256 * i;
      int r = l >> 3, cv = l & 7;
      *(uint4*)&Ks[r][cv * 8] = *(const uint4*)(kp + (size_t)(kt * 64 + r) * 1024 + cv * 8);
      U4 u; u.u = *(const uint4*)(vp + (size_t)(kt * 64 + r) * 1024 + cv * 8);
      #pragma unroll
      for (int j = 0; j < 8; ++j) Vts[cv * 8 + j][r] = u.s[j];
    }
    __syncthreads();
    bf16x8 a0 = *(const bf16x8*)&Qs[wv * 16 + l16][quad * 8];
    bf16x8 a1 = *(const bf16x8*)&Qs[wv * 16 + l16][32 + quad * 8];
    #pragma unroll
    for (int sn = 0; sn < 4; ++sn) {
      bf16x8 b0 = *(const bf16x8*)&Ks[sn * 16 + l16][quad * 8];
      bf16x8 b1 = *(const bf16x8*)&Ks[sn * 16 + l16][32 + quad * 8];
      f32x4 sacc = zero;
      sacc = __builtin_amdgcn_mfma_f32_16x16x32_bf16(a0, b0, sacc, 0, 0, 0);
      sacc = __builtin_amdgcn_mfma_f32_16x16x32_bf16(a1, b1, sacc, 0, 0, 0);
      int kidx = kt * 64 + sn * 16 + l16;
      int qbase_ = qt * 64 + wv * 16 + quad * 4;
      #pragma unroll
      for (int reg = 0; reg < 4; ++reg) {
        float xv = sacc[reg] * 0.125f;
        float gl = (kidx <= qbase_ + reg) ? gelu_f(xv) : 0.f;
        Sg[wv * 16 + quad * 4 + reg][sn * 16 + l16] = f2b(gl);
      }
    }
    __syncthreads();
    {
      int r = tid >> 2, qd = tid & 3;
      float s2 = 0.f;
      #pragma unroll
      for (int j = 0; j < 16; ++j) {
        float v = b2f(Sg[r][qd * 16 + j]);
        s2 += v * v;
      }
      ssq[r][qd] += s2;
    }
    bf16x8 p0 = *(const bf16x8*)&Sg[wv * 16 + l16][quad * 8];
    bf16x8 p1 = *(const bf16x8*)&Sg[wv * 16 + l16][32 + quad * 8];
    #pragma unroll
    for (int sn = 0; sn < 4; ++sn) {
      bf16x8 v0 = *(const bf16x8*)&Vts[sn * 16 + l16][quad * 8];
      bf16x8 v1 = *(const bf16x8*)&Vts[sn * 16 + l16][32 + quad * 8];
      oacc[sn] = __builtin_amdgcn_mfma_f32_16x16x32_bf16(p0, v0, oacc[sn], 0, 0, 0);
      oacc[sn] = __builtin_amdgcn_mfma_f32_16x16x32_bf16(p1, v1, oacc[sn], 0, 0, 0);
    }
    __syncthreads();
  }
  if (tid < 64)
    rowscale[tid] = sqrtf(2048.0f / (ssq[tid][0] + ssq[tid][1] + ssq[tid][2] + ssq[tid][3]));
  __syncthreads();
  #pragma unroll
  for (int sn = 0; sn < 4; ++sn) {
    #pragma unroll
    for (int reg = 0; reg < 4; ++reg) {
      int r = wv * 16 + quad * 4 + reg;
      int c = sn * 16 + l16;
      float v = oacc[sn][reg] * rowscale[r];
      ob[(size_t)(b * 2048 + qt * 64 + r) * 1024 + h * 64 + c] = f2b(v);
    }
  }
}

extern "C" void kernel_launch(void* const* d_in, const int* in_sizes, int n_in,
                              void* d_out, int out_size, void* d_ws, size_t ws_size,
                              hipStream_t stream) {
  const float* x    = (const float*)d_in[0];
  const float* ln1w = (const float*)d_in[1];
  const float* ln1b = (const float*)d_in[2];
  const float* ln2w = (const float*)d_in[3];
  const float* ln2b = (const float*)d_in[4];
  const float* qk   = (const float*)d_in[5];
  const float* qv   = (const float*)d_in[6];
  const float* kk   = (const float*)d_in[7];
  const float* kv   = (const float*)d_in[8];
  const float* vk   = (const float*)d_in[9];
  const float* vv   = (const float*)d_in[10];
  const float* pk   = (const float*)d_in[11];
  const float* pv   = (const float*)d_in[12];
  const float* fk   = (const float*)d_in[13];
  const float* fv   = (const float*)d_in[14];
  float* out = (float*)d_out;

  const size_t M1 = 1048576;
  u16* w = (u16*)d_ws;
  // key weights (NT-ready, [N,K]): q,k,v contiguous for z-batching
  u16* wkeys = w;                         // 3x 1M  (qk, kk, vk)
  u16* wpk   = w + 3 * M1;
  u16* wfk   = w + 4 * M1;                // 4M
  // val weights transposed to [H, P], q,k,v contiguous
  u16* wvalsT = w + 8 * M1;               // 3x 1M  (qvT, kvT, vvT)
  u16* wpvT   = w + 11 * M1;
  u16* wfvT   = w + 12 * M1;              // 4M  ([1024, 4096])
  // activations
  u16* xn = w + 16 * M1;                  // 4096x1024
  u16* g  = w + 20 * M1;                  // up to 16M elems (gq|gk|gv, proj-g, ffn-g)
  u16* qb = w + 36 * M1;                  // qb,kb,vb contiguous (z stride 4M)
  u16* kb = w + 40 * M1;
  u16* vb = w + 44 * M1;
  u16* ob = w + 48 * M1;
  float* x1 = (float*)(w + 52 * M1);      // fp32 4096x1024; total 120 MB

  dim3 blk(256);
  // weight conversions
  cvt_kernel<<<1024, blk, 0, stream>>>(qk, wkeys + 0 * M1, 262144);
  cvt_kernel<<<1024, blk, 0, stream>>>(kk, wkeys + 1 * M1, 262144);
  cvt_kernel<<<1024, blk, 0, stream>>>(vk, wkeys + 2 * M1, 262144);
  cvt_kernel<<<1024, blk, 0, stream>>>(pk, wpk, 262144);
  cvt_kernel<<<4096, blk, 0, stream>>>(fk, wfk, 1048576);
  cvtT_kernel<<<dim3(32, 32), blk, 0, stream>>>(qv, wvalsT + 0 * M1, 1024, 1024);
  cvtT_kernel<<<dim3(32, 32), blk, 0, stream>>>(kv, wvalsT + 1 * M1, 1024, 1024);
  cvtT_kernel<<<dim3(32, 32), blk, 0, stream>>>(vv, wvalsT + 2 * M1, 1024, 1024);
  cvtT_kernel<<<dim3(32, 32), blk, 0, stream>>>(pv, wpvT, 1024, 1024);
  cvtT_kernel<<<dim3(32, 128), blk, 0, stream>>>(fv, wfvT, 4096, 1024);

  ln_kernel<<<4096, blk, 0, stream>>>(x, ln1w, ln1b, xn);
  // q/k/v keys, z-batched: g_z = gelu(32 * xn . key_z^T)
  gemm_nt<64, false><<<dim3(8, 64, 3), blk, 0, stream>>>(
      xn, 0, wkeys, M1, g, 4 * M1, 1024, 1024, 32.0f, 1, nullptr);
  rownorm_kernel<<<12288, blk, 0, stream>>>(g, 1024, 32.0f);
  // q/k/v vals, z-batched: {qb,kb,vb} = g_z . valT_z^T
  gemm_nt<64, false><<<dim3(8, 64, 3), blk, 0, stream>>>(
      g, 4 * M1, wvalsT, M1, qb, 4 * M1, 1024, 1024, 1.0f, 0, nullptr);

  rotary_kernel<<<256, blk, 0, stream>>>(qb, kb);
  attn_kernel<<<dim3(32, 32), blk, 0, stream>>>(qb, kb, vb, ob);

  // proj
  gemm_nt<64, false><<<dim3(8, 64, 1), blk, 0, stream>>>(
      ob, 0, wpk, 0, g, 0, 1024, 1024, 32.0f, 1, nullptr);
  rownorm_kernel<<<4096, blk, 0, stream>>>(g, 1024, 32.0f);
  gemm_nt<64, true><<<dim3(8, 64, 1), blk, 0, stream>>>(
      g, 0, wpvT, 0, x1, 0, 1024, 1024, 1.0f, 0, x);

  // ffn
  ln_kernel<<<4096, blk, 0, stream>>>(x1, ln2w, ln2b, xn);
  gemm_nt<128, false><<<dim3(32, 32, 1), blk, 0, stream>>>(
      xn, 0, wfk, 0, g, 0, 4096, 1024, 32.0f, 1, nullptr);
  rownorm_kernel<<<4096, blk, 0, stream>>>(g, 4096, 64.0f);
  gemm_nt<64, true><<<dim3(8, 64, 1), blk, 0, stream>>>(
      g, 0, wfvT, 0, out, 0, 1024, 4096, 1.0f, 0, x1);
}

// Round 4
// 529.347 us; speedup vs baseline: 1.9076x; 1.2458x over previous
//
#include <hip/hip_runtime.h>

typedef __bf16 bf16x8 __attribute__((ext_vector_type(8)));
typedef float f32x4 __attribute__((ext_vector_type(4)));
typedef unsigned short u16;

__device__ __forceinline__ float b2f(u16 u) {
  union { unsigned int i; float f; } v; v.i = ((unsigned int)u) << 16; return v.f;
}
__device__ __forceinline__ u16 f2b(float f) {
  union { float f; unsigned int i; } v; v.f = f;
  unsigned int x = v.i;
  x += 0x7fffu + ((x >> 16) & 1u);   // round-to-nearest-even
  return (u16)(x >> 16);
}
// fast tanh-gelu: 0.5x(1+tanh(0.79788x(1+0.044715x^2))) = x - x/(1+exp(p))
// |err| vs erf-gelu ~3e-4; saturates to exact 0 / x for large |x|.
__device__ __forceinline__ float gelu_f(float x) {
  float x2 = x * x;
  float p = x * (1.5957691216f + 0.0713548162f * x2);
  float e = __expf(p);
  float r = __builtin_amdgcn_rcpf(1.0f + e);
  return x - x * r;
}
__device__ __forceinline__ void async16(const u16* g, u16* l) {
  __builtin_amdgcn_global_load_lds(
      (const __attribute__((address_space(1))) void*)g,
      (__attribute__((address_space(3))) void*)l, 16, 0, 0);
}

union U4 { uint4 u; u16 s[8]; };

// ---------------- zero fp32 ----------------
__global__ __launch_bounds__(256) void zero_kernel(float* __restrict__ p, int n) {
  int i = blockIdx.x * 256 + threadIdx.x;
  if (i < n) p[i] = 0.f;
}

// ---------------- fp32 -> bf16 convert ----------------
__global__ __launch_bounds__(256) void cvt_kernel(const float* __restrict__ in,
                                                  u16* __restrict__ out, int n4) {
  int i = blockIdx.x * 256 + threadIdx.x;
  if (i < n4) {
    float4 f = ((const float4*)in)[i];
    ushort4 o;
    o.x = f2b(f.x); o.y = f2b(f.y); o.z = f2b(f.z); o.w = f2b(f.w);
    ((ushort4*)out)[i] = o;
  }
}
__global__ __launch_bounds__(256) void cvt4_kernel(
    const float* __restrict__ a, const float* __restrict__ b,
    const float* __restrict__ c, const float* __restrict__ d,
    u16* __restrict__ out, int n4) {
  int z = blockIdx.y;
  const float* in = (z == 0) ? a : (z == 1) ? b : (z == 2) ? c : d;
  u16* o = out + (size_t)z * (size_t)n4 * 4;
  int i = blockIdx.x * 256 + threadIdx.x;
  if (i < n4) {
    float4 f = ((const float4*)in)[i];
    ushort4 s;
    s.x = f2b(f.x); s.y = f2b(f.y); s.z = f2b(f.z); s.w = f2b(f.w);
    ((ushort4*)o)[i] = s;
  }
}

// ---------------- fp32 [R,Cn] -> bf16 transposed [Cn,R] ----------------
__global__ __launch_bounds__(256) void cvtT_kernel(const float* __restrict__ in,
                                                   u16* __restrict__ out, int R, int Cn) {
  __shared__ float t[32][33];
  int bc = blockIdx.x, br = blockIdx.y;
  int tid = threadIdx.x;
  int r = tid >> 5, c = tid & 31;
  #pragma unroll
  for (int i = 0; i < 4; ++i)
    t[r + i * 8][c] = in[(size_t)(br * 32 + r + i * 8) * Cn + bc * 32 + c];
  __syncthreads();
  #pragma unroll
  for (int i = 0; i < 4; ++i)
    out[(size_t)(bc * 32 + r + i * 8) * R + br * 32 + c] = f2b(t[c][r + i * 8]);
}
__global__ __launch_bounds__(256) void cvtT4_kernel(
    const float* __restrict__ a, const float* __restrict__ b,
    const float* __restrict__ c, const float* __restrict__ d,
    u16* __restrict__ out) {
  __shared__ float t[32][33];
  int z = blockIdx.z;
  const float* in = (z == 0) ? a : (z == 1) ? b : (z == 2) ? c : d;
  u16* o = out + (size_t)z * 1048576;
  int bc = blockIdx.x, br = blockIdx.y;
  int tid = threadIdx.x;
  int r = tid >> 5, cc = tid & 31;
  #pragma unroll
  for (int i = 0; i < 4; ++i)
    t[r + i * 8][cc] = in[(size_t)(br * 32 + r + i * 8) * 1024 + bc * 32 + cc];
  __syncthreads();
  #pragma unroll
  for (int i = 0; i < 4; ++i)
    o[(size_t)(bc * 32 + r + i * 8) * 1024 + br * 32 + cc] = f2b(t[cc][r + i * 8]);
}

// ---------------- LayerNorm: fp32 in, bf16 out, rows of 1024 ----------------
__global__ __launch_bounds__(256) void ln_kernel(const float* __restrict__ x,
    const float* __restrict__ w, const float* __restrict__ b, u16* __restrict__ out) {
  int row = blockIdx.x;
  const float* xr = x + (size_t)row * 1024;
  u16* orow = out + (size_t)row * 1024;
  int tid = threadIdx.x;
  float vals[4];
  float s = 0.f, s2 = 0.f;
  #pragma unroll
  for (int i = 0; i < 4; ++i) {
    float v = xr[tid + 256 * i];
    vals[i] = v; s += v; s2 += v * v;
  }
  __shared__ float rs_[256], rs2_[256];
  rs_[tid] = s; rs2_[tid] = s2;
  __syncthreads();
  for (int st = 128; st > 0; st >>= 1) {
    if (tid < st) { rs_[tid] += rs_[tid + st]; rs2_[tid] += rs2_[tid + st]; }
    __syncthreads();
  }
  float mu = rs_[0] * (1.0f / 1024.0f);
  float var = rs2_[0] * (1.0f / 1024.0f) - mu * mu;
  float inv = rsqrtf(var + 1e-5f);
  #pragma unroll
  for (int i = 0; i < 4; ++i) {
    int c = tid + 256 * i;
    orow[c] = f2b((vals[i] - mu) * inv * w[c] + b[c]);
  }
}

// ---------------- key-GEMM: g = gelu(alpha * A.B^T), ssq[row] += sum g^2 ----------------
template <int TM>
__global__ __launch_bounds__(256) void gemm_key(
    const u16* __restrict__ A, size_t sAz,
    const u16* __restrict__ B, size_t sBz,
    u16* __restrict__ C, size_t sCz,
    float* __restrict__ ssqb, size_t sSz,
    int N, int K, float alpha) {
  constexpr int AI = TM / 32;
  __shared__ __align__(16) u16 As[TM * 32];
  __shared__ __align__(16) u16 Bs[128 * 32];
  int bn = blockIdx.x, bm = blockIdx.y, bz = blockIdx.z;
  const u16* Ab = A + (size_t)bz * sAz + (size_t)bm * TM * K;
  const u16* Bb = B + (size_t)bz * sBz + (size_t)bn * 128 * K;
  int tid = threadIdx.x, lane = tid & 63, wv = tid >> 6;
  int quad = lane >> 4, l16 = lane & 15;
  int lr = lane >> 2, lc = (lane & 3) * 8;
  int wm = wv >> 1, wn = wv & 1;
  int RB = wm * (TM / 2), CB = wn * 64;
  f32x4 zero = {0.f, 0.f, 0.f, 0.f};
  f32x4 acc[AI][4];
  #pragma unroll
  for (int i = 0; i < AI; ++i)
    #pragma unroll
    for (int j = 0; j < 4; ++j) acc[i][j] = zero;
  for (int k0 = 0; k0 < K; k0 += 32) {
    #pragma unroll
    for (int t = 0; t < TM / 64; ++t) {
      int ia = wv * (TM / 64) + t;
      async16(Ab + (size_t)(ia * 16 + lr) * K + k0 + lc, &As[ia * 512]);
    }
    #pragma unroll
    for (int t = 0; t < 2; ++t) {
      int ib = wv * 2 + t;
      async16(Bb + (size_t)(ib * 16 + lr) * K + k0 + lc, &Bs[ib * 512]);
    }
    __syncthreads();
    bf16x8 af[AI], bf[4];
    #pragma unroll
    for (int i = 0; i < AI; ++i)
      af[i] = *(const bf16x8*)&As[(RB + i * 16 + l16) * 32 + quad * 8];
    #pragma unroll
    for (int j = 0; j < 4; ++j)
      bf[j] = *(const bf16x8*)&Bs[(CB + j * 16 + l16) * 32 + quad * 8];
    #pragma unroll
    for (int i = 0; i < AI; ++i)
      #pragma unroll
      for (int j = 0; j < 4; ++j)
        acc[i][j] = __builtin_amdgcn_mfma_f32_16x16x32_bf16(af[i], bf[j], acc[i][j], 0, 0, 0);
    __syncthreads();
  }
  #pragma unroll
  for (int i = 0; i < AI; ++i) {
    int rbase = bm * TM + RB + i * 16 + quad * 4;
    float srow[4] = {0.f, 0.f, 0.f, 0.f};
    #pragma unroll
    for (int j = 0; j < 4; ++j) {
      int c = bn * 128 + CB + j * 16 + l16;
      #pragma unroll
      for (int reg = 0; reg < 4; ++reg) {
        float g = gelu_f(acc[i][j][reg] * alpha);
        srow[reg] += g * g;
        C[(size_t)bz * sCz + (size_t)(rbase + reg) * N + c] = f2b(g);
      }
    }
    #pragma unroll
    for (int reg = 0; reg < 4; ++reg) {
      float s = srow[reg];
      s += __shfl_xor(s, 1); s += __shfl_xor(s, 2);
      s += __shfl_xor(s, 4); s += __shfl_xor(s, 8);
      if (l16 == 0) atomicAdd(&ssqb[bz * sSz + rbase + reg], s);
    }
  }
}

// ---------------- val-GEMM: out = scale(row) * (g.B^T) [+res] ----------------
// MODE 0: bf16 store, *scale ; 1: f32 store, *scale + res ; 2: f32 raw partial (split-K)
template <int TM, int MODE>
__global__ __launch_bounds__(256) void gemm_val(
    const u16* __restrict__ A, size_t sAz,
    const u16* __restrict__ B, size_t sBz,
    void* __restrict__ C, size_t sCz,
    const float* __restrict__ ssqb, size_t sSz,
    int N, int K, int kzs, int klen, float sqrtP, const float* __restrict__ res) {
  constexpr int AI = TM / 32;
  __shared__ __align__(16) u16 As[TM * 32];
  __shared__ __align__(16) u16 Bs[128 * 32];
  int bn = blockIdx.x, bm = blockIdx.y, bz = blockIdx.z;
  const u16* Ab = A + (size_t)bz * sAz + (size_t)bm * TM * K;
  const u16* Bb = B + (size_t)bz * sBz + (size_t)bn * 128 * K;
  int tid = threadIdx.x, lane = tid & 63, wv = tid >> 6;
  int quad = lane >> 4, l16 = lane & 15;
  int lr = lane >> 2, lc = (lane & 3) * 8;
  int wm = wv >> 1, wn = wv & 1;
  int RB = wm * (TM / 2), CB = wn * 64;
  f32x4 zero = {0.f, 0.f, 0.f, 0.f};
  f32x4 acc[AI][4];
  #pragma unroll
  for (int i = 0; i < AI; ++i)
    #pragma unroll
    for (int j = 0; j < 4; ++j) acc[i][j] = zero;
  int kb0 = bz * kzs;
  for (int k0 = kb0; k0 < kb0 + klen; k0 += 32) {
    #pragma unroll
    for (int t = 0; t < TM / 64; ++t) {
      int ia = wv * (TM / 64) + t;
      async16(Ab + (size_t)(ia * 16 + lr) * K + k0 + lc, &As[ia * 512]);
    }
    #pragma unroll
    for (int t = 0; t < 2; ++t) {
      int ib = wv * 2 + t;
      async16(Bb + (size_t)(ib * 16 + lr) * K + k0 + lc, &Bs[ib * 512]);
    }
    __syncthreads();
    bf16x8 af[AI], bf[4];
    #pragma unroll
    for (int i = 0; i < AI; ++i)
      af[i] = *(const bf16x8*)&As[(RB + i * 16 + l16) * 32 + quad * 8];
    #pragma unroll
    for (int j = 0; j < 4; ++j)
      bf[j] = *(const bf16x8*)&Bs[(CB + j * 16 + l16) * 32 + quad * 8];
    #pragma unroll
    for (int i = 0; i < AI; ++i)
      #pragma unroll
      for (int j = 0; j < 4; ++j)
        acc[i][j] = __builtin_amdgcn_mfma_f32_16x16x32_bf16(af[i], bf[j], acc[i][j], 0, 0, 0);
    __syncthreads();
  }
  #pragma unroll
  for (int i = 0; i < AI; ++i) {
    int rbase = bm * TM + RB + i * 16 + quad * 4;
    float sc[4];
    if (MODE < 2) {
      #pragma unroll
      for (int reg = 0; reg < 4; ++reg)
        sc[reg] = sqrtP * rsqrtf(ssqb[bz * sSz + rbase + reg]);
    }
    #pragma unroll
    for (int j = 0; j < 4; ++j) {
      int c = bn * 128 + CB + j * 16 + l16;
      #pragma unroll
      for (int reg = 0; reg < 4; ++reg) {
        float v = acc[i][j][reg];
        size_t idx = (size_t)(rbase + reg) * N + c;
        if (MODE == 0) {
          ((u16*)C)[(size_t)bz * sCz + idx] = f2b(v * sc[reg]);
        } else if (MODE == 1) {
          ((float*)C)[idx] = v * sc[reg] + res[idx];
        } else {
          ((float*)C)[(size_t)bz * sCz + idx] = v;
        }
      }
    }
  }
}

// ---------------- rotary (in place, bf16) on first 16 dims of each head ----------------
__global__ __launch_bounds__(256) void rotary_kernel(u16* __restrict__ qb, u16* __restrict__ kb) {
  int t = blockIdx.x * 256 + threadIdx.x;
  int m = t >> 4;
  int h = t & 15;
  int s = m & 2047;
  u16* qp = qb + (size_t)m * 1024 + h * 64;
  u16* kp = kb + (size_t)m * 1024 + h * 64;
  float q[16], k[16];
  #pragma unroll
  for (int d = 0; d < 16; ++d) { q[d] = b2f(qp[d]); k[d] = b2f(kp[d]); }
  #pragma unroll
  for (int i = 0; i < 8; ++i) {
    float invf = powf(10000.0f, -(float)i * 0.125f);
    float ang = (float)s * invf;
    float c = cosf(ang), sn = sinf(ang);
    qp[i]     = f2b(q[i] * c - q[i + 8] * sn);
    qp[i + 8] = f2b(q[i + 8] * c + q[i] * sn);
    kp[i]     = f2b(k[i] * c - k[i + 8] * sn);
    kp[i + 8] = f2b(k[i + 8] * c + k[i] * sn);
  }
}

// ---------------- per-head V transpose: vb[b,s,h*64+d] -> vT[bh,d,s] ----------------
__global__ __launch_bounds__(256) void vt_kernel(const u16* __restrict__ vb,
                                                 u16* __restrict__ vT) {
  __shared__ __align__(16) u16 T[64][72];
  int st = blockIdx.x, bh = blockIdx.y;
  int b = bh >> 4, h = bh & 15;
  int tid = threadIdx.x;
  #pragma unroll
  for (int i = 0; i < 2; ++i) {
    int l = tid + 256 * i;
    int s = l >> 3, dc = l & 7;
    *(uint4*)&T[s][dc * 8] =
        *(const uint4*)(vb + (size_t)(b * 2048 + st * 64 + s) * 1024 + h * 64 + dc * 8);
  }
  __syncthreads();
  #pragma unroll
  for (int i = 0; i < 2; ++i) {
    int l = tid + 256 * i;
    int d = l >> 3, scid = l & 7;
    U4 u;
    #pragma unroll
    for (int j = 0; j < 8; ++j) u.s[j] = T[scid * 8 + j][d];
    *(uint4*)(vT + ((size_t)bh * 64 + d) * 2048 + st * 64 + scid * 8) = u.u;
  }
}

// ---------------- fused causal attention + gelu_l2_norm over keys ----------------
// TQ=128 q-rows/block, TK=64. gelu_l2_norm is a linear rescale: accumulate raw
// O and per-row sum(g^2) in registers, scale at end by sqrt(2048/ssq).
__global__ __launch_bounds__(256) void attn_kernel(
    const u16* __restrict__ qb, const u16* __restrict__ kb,
    const u16* __restrict__ vT, u16* __restrict__ ob) {
  __shared__ __align__(16) u16 Qs[128 * 64];   // 16 KB
  __shared__ __align__(16) u16 Ks[64 * 64];    // 8 KB
  __shared__ __align__(16) u16 Vts[64 * 64];   // 8 KB
  __shared__ __align__(16) u16 Sg[128 * 72];   // 18 KB (stride 72: b128-conflict-free)
  int bh = blockIdx.x, pr = blockIdx.y;
  int qt = (pr < 8) ? pr : 23 - pr;            // pairs long+short tiles per CU
  int b = bh >> 4, h = bh & 15;
  const u16* qp = qb + (size_t)b * 2048 * 1024 + h * 64;
  const u16* kp = kb + (size_t)b * 2048 * 1024 + h * 64;
  const u16* vp = vT + (size_t)bh * 64 * 2048;
  int tid = threadIdx.x, lane = tid & 63, wv = tid >> 6;
  int quad = lane >> 4, l16 = lane & 15;
  int lr8 = lane >> 3, lc8 = (lane & 7) * 8;
  int MR = wv * 32;
  int nkt = 2 * qt + 2;
  #pragma unroll
  for (int t = 0; t < 4; ++t) {                // stage Q once
    int idx = wv * 4 + t;
    async16(qp + (size_t)(qt * 128 + idx * 8 + lr8) * 1024 + lc8, &Qs[idx * 512]);
  }
  #pragma unroll
  for (int t = 0; t < 2; ++t) {                // stage K/V tile 0
    int idx = wv * 2 + t;
    async16(kp + (size_t)(idx * 8 + lr8) * 1024 + lc8, &Ks[idx * 512]);
    async16(vp + (size_t)(idx * 8 + lr8) * 2048 + lc8, &Vts[idx * 512]);
  }
  f32x4 zero = {0.f, 0.f, 0.f, 0.f};
  f32x4 oacc[2][4];
  float ssqr[2][4];
  #pragma unroll
  for (int mf = 0; mf < 2; ++mf) {
    #pragma unroll
    for (int dn = 0; dn < 4; ++dn) oacc[mf][dn] = zero;
    #pragma unroll
    for (int r = 0; r < 4; ++r) ssqr[mf][r] = 0.f;
  }
  for (int kt = 0; kt < nkt; ++kt) {
    __syncthreads();                           // staging(kt) done; prior Sg reads done
    bf16x8 bv[4][2];                           // hoist V frags so restage can overlap PV
    #pragma unroll
    for (int dn = 0; dn < 4; ++dn)
      #pragma unroll
      for (int kc = 0; kc < 2; ++kc)
        bv[dn][kc] = *(const bf16x8*)&Vts[(dn * 16 + l16) * 64 + kc * 32 + quad * 8];
    #pragma unroll
    for (int mf = 0; mf < 2; ++mf) {           // S = QK^T/8, mask, gelu -> Sg + ssq
      bf16x8 a0 = *(const bf16x8*)&Qs[(MR + mf * 16 + l16) * 64 + quad * 8];
      bf16x8 a1 = *(const bf16x8*)&Qs[(MR + mf * 16 + l16) * 64 + 32 + quad * 8];
      #pragma unroll
      for (int sn = 0; sn < 4; ++sn) {
        bf16x8 b0 = *(const bf16x8*)&Ks[(sn * 16 + l16) * 64 + quad * 8];
        bf16x8 b1 = *(const bf16x8*)&Ks[(sn * 16 + l16) * 64 + 32 + quad * 8];
        f32x4 s = zero;
        s = __builtin_amdgcn_mfma_f32_16x16x32_bf16(a0, b0, s, 0, 0, 0);
        s = __builtin_amdgcn_mfma_f32_16x16x32_bf16(a1, b1, s, 0, 0, 0);
        int srow = MR + mf * 16 + quad * 4;
        int kcol = kt * 64 + sn * 16 + l16;
        bool dg = (kt >= 2 * qt);              // only diagonal tiles need masking
        #pragma unroll
        for (int reg = 0; reg < 4; ++reg) {
          float gl = gelu_f(s[reg] * 0.125f);
          if (dg && kcol > qt * 128 + srow + reg) gl = 0.f;
          ssqr[mf][reg] += gl * gl;
          Sg[(srow + reg) * 72 + sn * 16 + l16] = f2b(gl);
        }
      }
    }
    __syncthreads();                           // all Ks/Vts reads done -> safe to restage
    if (kt + 1 < nkt) {
      #pragma unroll
      for (int t = 0; t < 2; ++t) {            // overlaps PV-MFMA below
        int idx = wv * 2 + t;
        async16(kp + (size_t)((kt + 1) * 64 + idx * 8 + lr8) * 1024 + lc8, &Ks[idx * 512]);
        async16(vp + (size_t)(idx * 8 + lr8) * 2048 + (kt + 1) * 64 + lc8, &Vts[idx * 512]);
      }
    }
    #pragma unroll
    for (int mf = 0; mf < 2; ++mf) {           // O += P.V (P from own-wave Sg rows)
      bf16x8 p0 = *(const bf16x8*)&Sg[(MR + mf * 16 + l16) * 72 + quad * 8];
      bf16x8 p1 = *(const bf16x8*)&Sg[(MR + mf * 16 + l16) * 72 + 32 + quad * 8];
      #pragma unroll
      for (int dn = 0; dn < 4; ++dn) {
        oacc[mf][dn] = __builtin_amdgcn_mfma_f32_16x16x32_bf16(p0, bv[dn][0], oacc[mf][dn], 0, 0, 0);
        oacc[mf][dn] = __builtin_amdgcn_mfma_f32_16x16x32_bf16(p1, bv[dn][1], oacc[mf][dn], 0, 0, 0);
      }
    }
  }
  #pragma unroll
  for (int mf = 0; mf < 2; ++mf) {
    float sc[4];
    #pragma unroll
    for (int reg = 0; reg < 4; ++reg) {
      float s = ssqr[mf][reg];
      s += __shfl_xor(s, 1); s += __shfl_xor(s, 2);
      s += __shfl_xor(s, 4); s += __shfl_xor(s, 8);
      sc[reg] = 45.254834f * rsqrtf(s);        // sqrt(2048/ssq)
    }
    #pragma unroll
    for (int dn = 0; dn < 4; ++dn)
      #pragma unroll
      for (int reg = 0; reg < 4; ++reg) {
        int row = qt * 128 + MR + mf * 16 + quad * 4 + reg;
        int col = h * 64 + dn * 16 + l16;
        ob[(size_t)(b * 2048 + row) * 1024 + col] = f2b(oacc[mf][dn][reg] * sc[reg]);
      }
  }
}

// ---------------- finalize: out = x1 + 64*rsqrt(ssq)[row] * (p0+p1) ----------------
__global__ __launch_bounds__(256) void fin_kernel(
    const float* __restrict__ p0, const float* __restrict__ p1,
    const float* __restrict__ x1, const float* __restrict__ ssqf,
    float* __restrict__ out) {
  int row = blockIdx.x, t = threadIdx.x;
  float s = 64.0f * rsqrtf(ssqf[row]);
  size_t base = (size_t)row * 1024 + t * 4;
  float4 a = *(const float4*)(p0 + base);
  float4 b = *(const float4*)(p1 + base);
  float4 r = *(const float4*)(x1 + base);
  float4 o;
  o.x = r.x + s * (a.x + b.x); o.y = r.y + s * (a.y + b.y);
  o.z = r.z + s * (a.z + b.z); o.w = r.w + s * (a.w + b.w);
  *(float4*)(out + base) = o;
}

extern "C" void kernel_launch(void* const* d_in, const int* in_sizes, int n_in,
                              void* d_out, int out_size, void* d_ws, size_t ws_size,
                              hipStream_t stream) {
  const float* x    = (const float*)d_in[0];
  const float* ln1w = (const float*)d_in[1];
  const float* ln1b = (const float*)d_in[2];
  const float* ln2w = (const float*)d_in[3];
  const float* ln2b = (const float*)d_in[4];
  const float* qk   = (const float*)d_in[5];
  const float* qv   = (const float*)d_in[6];
  const float* kk   = (const float*)d_in[7];
  const float* kv   = (const float*)d_in[8];
  const float* vk   = (const float*)d_in[9];
  const float* vv   = (const float*)d_in[10];
  const float* pk   = (const float*)d_in[11];
  const float* pv   = (const float*)d_in[12];
  const float* fk   = (const float*)d_in[13];
  const float* fv   = (const float*)d_in[14];
  float* out = (float*)d_out;

  const size_t M1 = 1048576;
  u16* w = (u16*)d_ws;
  // layout (u16 units), 60M total = 120 MiB:
  u16* wkeys  = w;                  // 0..3M   (qk,kk,vk)   | later p0 covers 0..8M
  u16* wpk    = w + 3 * M1;
  u16* wfk    = w + 4 * M1;         // 4M..8M
  u16* wvalsT = w + 8 * M1;         // 8..11M  (qvT,kvT,vvT)
  u16* wpvT   = w + 11 * M1;
  u16* wfvT   = w + 12 * M1;        // 12..16M
  u16* xn     = w + 16 * M1;        // 16..20M
  u16* gq     = w + 20 * M1;        // qkv ghat z-stride 4M (20..32M); later ob/gp/gf
  u16* ob     = w + 20 * M1;
  u16* gp     = w + 24 * M1;
  u16* gf     = w + 20 * M1;        // ffn ghat 20..36M
  u16* qb     = w + 36 * M1;        // 36..40M  | later p1 covers 36..44M
  u16* kb     = w + 40 * M1;
  u16* vb     = w + 44 * M1;
  u16* vT     = w + 48 * M1;        // 48..52M (ssq overlays its head; vT written after qkv)
  float* ssq_qkv  = (float*)(w + 48 * M1);   // 3*4096 f
  float* ssq_proj = ssq_qkv + 12288;         // 4096 f
  float* ssq_ffn  = ssq_qkv + 16384;         // 4096 f
  float* x1 = (float*)(w + 52 * M1);         // 52..60M (4M f32)
  float* p0 = (float*)w;                     // ffn partial z=0 (weights dead by then)
  float* p1 = (float*)(w + 36 * M1);         // ffn partial z=1 (qb/kb dead)

  dim3 blk(256);
  zero_kernel<<<80, blk, 0, stream>>>(ssq_qkv, 20480);
  cvt4_kernel<<<dim3(1024, 4), blk, 0, stream>>>(qk, kk, vk, pk, wkeys, 262144);
  cvt_kernel<<<4096, blk, 0, stream>>>(fk, wfk, 1048576);
  cvtT4_kernel<<<dim3(32, 32, 4), blk, 0, stream>>>(qv, kv, vv, pv, wvalsT);
  cvtT_kernel<<<dim3(32, 128), blk, 0, stream>>>(fv, wfvT, 4096, 1024);

  ln_kernel<<<4096, blk, 0, stream>>>(x, ln1w, ln1b, xn);
  // qkv: ghat_z = gelu(32 * xn.key_z^T) + ssq ; then {qb,kb,vb} = scale*(ghat_z.val_z)
  gemm_key<128><<<dim3(8, 32, 3), blk, 0, stream>>>(
      xn, 0, wkeys, M1, gq, 4 * M1, ssq_qkv, 4096, 1024, 1024, 32.0f);
  gemm_val<128, 0><<<dim3(8, 32, 3), blk, 0, stream>>>(
      gq, 4 * M1, wvalsT, M1, qb, 4 * M1, ssq_qkv, 4096, 1024, 1024, 0, 1024, 32.0f, nullptr);

  rotary_kernel<<<256, blk, 0, stream>>>(qb, kb);
  vt_kernel<<<dim3(32, 32), blk, 0, stream>>>(vb, vT);
  attn_kernel<<<dim3(32, 16), blk, 0, stream>>>(qb, kb, vT, ob);
  zero_kernel<<<32, blk, 0, stream>>>(ssq_proj, 8192);   // vT head dead after attn

  // proj: x1 = x + scale*(gelu(32*ob.pk^T).pv)
  gemm_key<64><<<dim3(8, 64, 1), blk, 0, stream>>>(
      ob, 0, wpk, 0, gp, 0, ssq_proj, 0, 1024, 1024, 32.0f);
  gemm_val<64, 1><<<dim3(8, 64, 1), blk, 0, stream>>>(
      gp, 0, wpvT, 0, x1, 0, ssq_proj, 0, 1024, 1024, 0, 1024, 32.0f, x);

  // ffn: out = x1 + scale*(gelu(32*ln(x1).fk^T).fv)   (split-K=2 + finalize)
  ln_kernel<<<4096, blk, 0, stream>>>(x1, ln2w, ln2b, xn);
  gemm_key<128><<<dim3(32, 32, 1), blk, 0, stream>>>(
      xn, 0, wfk, 0, gf, 0, ssq_ffn, 0, 4096, 1024, 32.0f);
  gemm_val<128, 2><<<dim3(8, 32, 2), blk, 0, stream>>>(
      gf, 0, wfvT, 0, p0, 18 * M1, ssq_ffn, 0, 1024, 4096, 2048, 2048, 0.0f, nullptr);
  fin_kernel<<<4096, blk, 0, stream>>>(p0, p1, x1, ssq_ffn, out);
}

// Round 5
// 486.933 us; speedup vs baseline: 2.0738x; 1.0871x over previous
//
#include <hip/hip_runtime.h>

typedef __bf16 bf16x8 __attribute__((ext_vector_type(8)));
typedef float f32x4 __attribute__((ext_vector_type(4)));
typedef unsigned short u16;

__device__ __forceinline__ float b2f(u16 u) {
  union { unsigned int i; float f; } v; v.i = ((unsigned int)u) << 16; return v.f;
}
__device__ __forceinline__ u16 f2b(float f) {
  union { float f; unsigned int i; } v; v.f = f;
  unsigned int x = v.i;
  x += 0x7fffu + ((x >> 16) & 1u);   // round-to-nearest-even
  return (u16)(x >> 16);
}
// fast tanh-gelu (validated R4: absmax 0.0625)
__device__ __forceinline__ float gelu_f(float x) {
  float x2 = x * x;
  float p = x * (1.5957691216f + 0.0713548162f * x2);
  float e = __expf(p);
  float r = __builtin_amdgcn_rcpf(1.0f + e);
  return x - x * r;
}
__device__ __forceinline__ void async16(const u16* g, u16* l) {
  __builtin_amdgcn_global_load_lds(
      (const __attribute__((address_space(1))) void*)g,
      (__attribute__((address_space(3))) void*)l, 16, 0, 0);
}

union U4 { uint4 u; u16 s[8]; };

// ---------------- zero fp32 ----------------
__global__ __launch_bounds__(256) void zero_kernel(float* __restrict__ p, int n) {
  int i = blockIdx.x * 256 + threadIdx.x;
  if (i < n) p[i] = 0.f;
}

// ---------------- fp32 -> bf16 convert ----------------
__global__ __launch_bounds__(256) void cvt_kernel(const float* __restrict__ in,
                                                  u16* __restrict__ out, int n4) {
  int i = blockIdx.x * 256 + threadIdx.x;
  if (i < n4) {
    float4 f = ((const float4*)in)[i];
    ushort4 o;
    o.x = f2b(f.x); o.y = f2b(f.y); o.z = f2b(f.z); o.w = f2b(f.w);
    ((ushort4*)out)[i] = o;
  }
}
__global__ __launch_bounds__(256) void cvt4_kernel(
    const float* __restrict__ a, const float* __restrict__ b,
    const float* __restrict__ c, const float* __restrict__ d,
    u16* __restrict__ out, int n4) {
  int z = blockIdx.y;
  const float* in = (z == 0) ? a : (z == 1) ? b : (z == 2) ? c : d;
  u16* o = out + (size_t)z * (size_t)n4 * 4;
  int i = blockIdx.x * 256 + threadIdx.x;
  if (i < n4) {
    float4 f = ((const float4*)in)[i];
    ushort4 s;
    s.x = f2b(f.x); s.y = f2b(f.y); s.z = f2b(f.z); s.w = f2b(f.w);
    ((ushort4*)o)[i] = s;
  }
}

// ---------------- fp32 [R,Cn] -> bf16 transposed [Cn,R] ----------------
__global__ __launch_bounds__(256) void cvtT_kernel(const float* __restrict__ in,
                                                   u16* __restrict__ out, int R, int Cn) {
  __shared__ float t[32][33];
  int bc = blockIdx.x, br = blockIdx.y;
  int tid = threadIdx.x;
  int r = tid >> 5, c = tid & 31;
  #pragma unroll
  for (int i = 0; i < 4; ++i)
    t[r + i * 8][c] = in[(size_t)(br * 32 + r + i * 8) * Cn + bc * 32 + c];
  __syncthreads();
  #pragma unroll
  for (int i = 0; i < 4; ++i)
    out[(size_t)(bc * 32 + r + i * 8) * R + br * 32 + c] = f2b(t[c][r + i * 8]);
}
__global__ __launch_bounds__(256) void cvtT4_kernel(
    const float* __restrict__ a, const float* __restrict__ b,
    const float* __restrict__ c, const float* __restrict__ d,
    u16* __restrict__ out) {
  __shared__ float t[32][33];
  int z = blockIdx.z;
  const float* in = (z == 0) ? a : (z == 1) ? b : (z == 2) ? c : d;
  u16* o = out + (size_t)z * 1048576;
  int bc = blockIdx.x, br = blockIdx.y;
  int tid = threadIdx.x;
  int r = tid >> 5, cc = tid & 31;
  #pragma unroll
  for (int i = 0; i < 4; ++i)
    t[r + i * 8][cc] = in[(size_t)(br * 32 + r + i * 8) * 1024 + bc * 32 + cc];
  __syncthreads();
  #pragma unroll
  for (int i = 0; i < 4; ++i)
    o[(size_t)(bc * 32 + r + i * 8) * 1024 + br * 32 + cc] = f2b(t[cc][r + i * 8]);
}

// ---------------- LayerNorm: wave-per-row, shuffle-only ----------------
__global__ __launch_bounds__(256) void ln_kernel(const float* __restrict__ x,
    const float* __restrict__ w, const float* __restrict__ b, u16* __restrict__ out) {
  int wv = threadIdx.x >> 6, lane = threadIdx.x & 63;
  int row = blockIdx.x * 4 + wv;
  const float* xr = x + (size_t)row * 1024;
  float4 v[4];
  float s = 0.f, s2 = 0.f;
  #pragma unroll
  for (int i = 0; i < 4; ++i) {
    v[i] = ((const float4*)xr)[lane + 64 * i];
    s += v[i].x + v[i].y + v[i].z + v[i].w;
    s2 += v[i].x * v[i].x + v[i].y * v[i].y + v[i].z * v[i].z + v[i].w * v[i].w;
  }
  #pragma unroll
  for (int m = 1; m < 64; m <<= 1) { s += __shfl_xor(s, m); s2 += __shfl_xor(s2, m); }
  float mu = s * (1.0f / 1024.0f);
  float inv = rsqrtf(s2 * (1.0f / 1024.0f) - mu * mu + 1e-5f);
  u16* orow = out + (size_t)row * 1024;
  #pragma unroll
  for (int i = 0; i < 4; ++i) {
    int c = (lane + 64 * i) * 4;
    ushort4 o;
    o.x = f2b((v[i].x - mu) * inv * w[c]     + b[c]);
    o.y = f2b((v[i].y - mu) * inv * w[c + 1] + b[c + 1]);
    o.z = f2b((v[i].z - mu) * inv * w[c + 2] + b[c + 2]);
    o.w = f2b((v[i].w - mu) * inv * w[c + 3] + b[c + 3]);
    ((ushort4*)orow)[lane + 64 * i] = o;
  }
}

// ---------------- key-GEMM (1-barrier dbuf): g = gelu(alpha*A.B^T), ssq += ----------------
template <int TM>
__global__ __launch_bounds__(256) void gemm_key(
    const u16* __restrict__ A, size_t sAz,
    const u16* __restrict__ B, size_t sBz,
    u16* __restrict__ C, size_t sCz,
    float* __restrict__ ssqb, size_t sSz,
    int N, int K, float alpha) {
  constexpr int AI = TM / 32;
  __shared__ __align__(16) u16 As[2][TM * 32];
  __shared__ __align__(16) u16 Bs[2][128 * 32];
  int bn = blockIdx.x, bm = blockIdx.y, bz = blockIdx.z;
  const u16* Ab = A + (size_t)bz * sAz + (size_t)bm * TM * K;
  const u16* Bb = B + (size_t)bz * sBz + (size_t)bn * 128 * K;
  int tid = threadIdx.x, lane = tid & 63, wv = tid >> 6;
  int quad = lane >> 4, l16 = lane & 15;
  int lr = lane >> 2, lc = (lane & 3) * 8;
  int wm = wv >> 1, wn = wv & 1;
  int RB = wm * (TM / 2), CB = wn * 64;
  f32x4 zero = {0.f, 0.f, 0.f, 0.f};
  f32x4 acc[AI][4];
  #pragma unroll
  for (int i = 0; i < AI; ++i)
    #pragma unroll
    for (int j = 0; j < 4; ++j) acc[i][j] = zero;
  // prologue stage k0=0 -> buf0
  #pragma unroll
  for (int t = 0; t < TM / 64; ++t) {
    int ia = wv * (TM / 64) + t;
    async16(Ab + (size_t)(ia * 16 + lr) * K + lc, &As[0][ia * 512]);
  }
  #pragma unroll
  for (int t = 0; t < 2; ++t) {
    int ib = wv * 2 + t;
    async16(Bb + (size_t)(ib * 16 + lr) * K + lc, &Bs[0][ib * 512]);
  }
  for (int k0 = 0, cur = 0; k0 < K; k0 += 32, cur ^= 1) {
    __syncthreads();
    if (k0 + 32 < K) {
      #pragma unroll
      for (int t = 0; t < TM / 64; ++t) {
        int ia = wv * (TM / 64) + t;
        async16(Ab + (size_t)(ia * 16 + lr) * K + k0 + 32 + lc, &As[cur ^ 1][ia * 512]);
      }
      #pragma unroll
      for (int t = 0; t < 2; ++t) {
        int ib = wv * 2 + t;
        async16(Bb + (size_t)(ib * 16 + lr) * K + k0 + 32 + lc, &Bs[cur ^ 1][ib * 512]);
      }
    }
    bf16x8 af[AI], bf[4];
    #pragma unroll
    for (int i = 0; i < AI; ++i)
      af[i] = *(const bf16x8*)&As[cur][(RB + i * 16 + l16) * 32 + quad * 8];
    #pragma unroll
    for (int j = 0; j < 4; ++j)
      bf[j] = *(const bf16x8*)&Bs[cur][(CB + j * 16 + l16) * 32 + quad * 8];
    #pragma unroll
    for (int i = 0; i < AI; ++i)
      #pragma unroll
      for (int j = 0; j < 4; ++j)
        acc[i][j] = __builtin_amdgcn_mfma_f32_16x16x32_bf16(af[i], bf[j], acc[i][j], 0, 0, 0);
  }
  #pragma unroll
  for (int i = 0; i < AI; ++i) {
    int rbase = bm * TM + RB + i * 16 + quad * 4;
    float srow[4] = {0.f, 0.f, 0.f, 0.f};
    #pragma unroll
    for (int j = 0; j < 4; ++j) {
      int c = bn * 128 + CB + j * 16 + l16;
      #pragma unroll
      for (int reg = 0; reg < 4; ++reg) {
        float g = gelu_f(acc[i][j][reg] * alpha);
        srow[reg] += g * g;
        C[(size_t)bz * sCz + (size_t)(rbase + reg) * N + c] = f2b(g);
      }
    }
    #pragma unroll
    for (int reg = 0; reg < 4; ++reg) {
      float s = srow[reg];
      s += __shfl_xor(s, 1); s += __shfl_xor(s, 2);
      s += __shfl_xor(s, 4); s += __shfl_xor(s, 8);
      if (l16 == 0) atomicAdd(&ssqb[bz * sSz + rbase + reg], s);
    }
  }
}

// ---------------- val-GEMM (1-barrier dbuf) ----------------
// MODE 0: bf16 store, *scale ; 1: f32 store, *scale + res ; 2: f32 raw partial (split-K)
template <int TM, int MODE>
__global__ __launch_bounds__(256) void gemm_val(
    const u16* __restrict__ A, size_t sAz,
    const u16* __restrict__ B, size_t sBz,
    void* __restrict__ C, size_t sCz,
    const float* __restrict__ ssqb, size_t sSz,
    int N, int K, int kzs, int klen, float sqrtP, const float* __restrict__ res) {
  constexpr int AI = TM / 32;
  __shared__ __align__(16) u16 As[2][TM * 32];
  __shared__ __align__(16) u16 Bs[2][128 * 32];
  int bn = blockIdx.x, bm = blockIdx.y, bz = blockIdx.z;
  const u16* Ab = A + (size_t)bz * sAz + (size_t)bm * TM * K;
  const u16* Bb = B + (size_t)bz * sBz + (size_t)bn * 128 * K;
  int tid = threadIdx.x, lane = tid & 63, wv = tid >> 6;
  int quad = lane >> 4, l16 = lane & 15;
  int lr = lane >> 2, lc = (lane & 3) * 8;
  int wm = wv >> 1, wn = wv & 1;
  int RB = wm * (TM / 2), CB = wn * 64;
  f32x4 zero = {0.f, 0.f, 0.f, 0.f};
  f32x4 acc[AI][4];
  #pragma unroll
  for (int i = 0; i < AI; ++i)
    #pragma unroll
    for (int j = 0; j < 4; ++j) acc[i][j] = zero;
  int kb0 = bz * kzs;
  #pragma unroll
  for (int t = 0; t < TM / 64; ++t) {
    int ia = wv * (TM / 64) + t;
    async16(Ab + (size_t)(ia * 16 + lr) * K + kb0 + lc, &As[0][ia * 512]);
  }
  #pragma unroll
  for (int t = 0; t < 2; ++t) {
    int ib = wv * 2 + t;
    async16(Bb + (size_t)(ib * 16 + lr) * K + kb0 + lc, &Bs[0][ib * 512]);
  }
  for (int k0 = kb0, cur = 0; k0 < kb0 + klen; k0 += 32, cur ^= 1) {
    __syncthreads();
    if (k0 + 32 < kb0 + klen) {
      #pragma unroll
      for (int t = 0; t < TM / 64; ++t) {
        int ia = wv * (TM / 64) + t;
        async16(Ab + (size_t)(ia * 16 + lr) * K + k0 + 32 + lc, &As[cur ^ 1][ia * 512]);
      }
      #pragma unroll
      for (int t = 0; t < 2; ++t) {
        int ib = wv * 2 + t;
        async16(Bb + (size_t)(ib * 16 + lr) * K + k0 + 32 + lc, &Bs[cur ^ 1][ib * 512]);
      }
    }
    bf16x8 af[AI], bf[4];
    #pragma unroll
    for (int i = 0; i < AI; ++i)
      af[i] = *(const bf16x8*)&As[cur][(RB + i * 16 + l16) * 32 + quad * 8];
    #pragma unroll
    for (int j = 0; j < 4; ++j)
      bf[j] = *(const bf16x8*)&Bs[cur][(CB + j * 16 + l16) * 32 + quad * 8];
    #pragma unroll
    for (int i = 0; i < AI; ++i)
      #pragma unroll
      for (int j = 0; j < 4; ++j)
        acc[i][j] = __builtin_amdgcn_mfma_f32_16x16x32_bf16(af[i], bf[j], acc[i][j], 0, 0, 0);
  }
  #pragma unroll
  for (int i = 0; i < AI; ++i) {
    int rbase = bm * TM + RB + i * 16 + quad * 4;
    float sc[4];
    if (MODE < 2) {
      #pragma unroll
      for (int reg = 0; reg < 4; ++reg)
        sc[reg] = sqrtP * rsqrtf(ssqb[bz * sSz + rbase + reg]);
    }
    #pragma unroll
    for (int j = 0; j < 4; ++j) {
      int c = bn * 128 + CB + j * 16 + l16;
      #pragma unroll
      for (int reg = 0; reg < 4; ++reg) {
        float v = acc[i][j][reg];
        size_t idx = (size_t)(rbase + reg) * N + c;
        if (MODE == 0) {
          ((u16*)C)[(size_t)bz * sCz + idx] = f2b(v * sc[reg]);
        } else if (MODE == 1) {
          ((float*)C)[idx] = v * sc[reg] + res[idx];
        } else {
          ((float*)C)[(size_t)bz * sCz + idx] = v;
        }
      }
    }
  }
}

// ---------------- rotary (in place, bf16) on first 16 dims of each head ----------------
__global__ __launch_bounds__(256) void rotary_kernel(u16* __restrict__ qb, u16* __restrict__ kb) {
  const float F[8] = {1.f, 0.31622776601683794f, 0.1f, 0.03162277660168379f,
                      0.01f, 0.0031622776601683794f, 0.001f, 0.00031622776601683794f};
  int t = blockIdx.x * 256 + threadIdx.x;
  int m = t >> 4;
  int h = t & 15;
  int s = m & 2047;
  u16* qp = qb + (size_t)m * 1024 + h * 64;
  u16* kp = kb + (size_t)m * 1024 + h * 64;
  float q[16], k[16];
  #pragma unroll
  for (int d = 0; d < 16; ++d) { q[d] = b2f(qp[d]); k[d] = b2f(kp[d]); }
  #pragma unroll
  for (int i = 0; i < 8; ++i) {
    float ang = (float)s * F[i];
    float c = cosf(ang), sn = sinf(ang);
    qp[i]     = f2b(q[i] * c - q[i + 8] * sn);
    qp[i + 8] = f2b(q[i + 8] * c + q[i] * sn);
    kp[i]     = f2b(k[i] * c - k[i + 8] * sn);
    kp[i + 8] = f2b(k[i + 8] * c + k[i] * sn);
  }
}

// ---------------- per-head V transpose: vb[b,s,h*64+d] -> vT[bh,d,s] ----------------
__global__ __launch_bounds__(256) void vt_kernel(const u16* __restrict__ vb,
                                                 u16* __restrict__ vT) {
  __shared__ __align__(16) u16 T[64][72];
  int st = blockIdx.x, bh = blockIdx.y;
  int b = bh >> 4, h = bh & 15;
  int tid = threadIdx.x;
  #pragma unroll
  for (int i = 0; i < 2; ++i) {
    int l = tid + 256 * i;
    int s = l >> 3, dc = l & 7;
    *(uint4*)&T[s][dc * 8] =
        *(const uint4*)(vb + (size_t)(b * 2048 + st * 64 + s) * 1024 + h * 64 + dc * 8);
  }
  __syncthreads();
  #pragma unroll
  for (int i = 0; i < 2; ++i) {
    int l = tid + 256 * i;
    int d = l >> 3, scid = l & 7;
    U4 u;
    #pragma unroll
    for (int j = 0; j < 8; ++j) u.s[j] = T[scid * 8 + j][d];
    *(uint4*)(vT + ((size_t)bh * 64 + d) * 2048 + st * 64 + scid * 8) = u.u;
  }
}

// ---------------- fused causal attention + gelu_l2_norm over keys ----------------
// TQ=64 per block; grid (bh, 32) with qt = 31-pr (heavy blocks dispatched first, LPT).
// Double-buffered K/V LDS, ONE barrier per kt-iter (Sg is same-wave write/read).
__global__ __launch_bounds__(256) void attn_kernel(
    const u16* __restrict__ qb, const u16* __restrict__ kb,
    const u16* __restrict__ vT, u16* __restrict__ ob) {
  __shared__ __align__(16) u16 Qs[64 * 64];       // 8 KB
  __shared__ __align__(16) u16 Ks[2][64 * 64];    // 16 KB
  __shared__ __align__(16) u16 Vts[2][64 * 64];   // 16 KB
  __shared__ __align__(16) u16 Sg[64 * 72];       // 9 KB
  int bh = blockIdx.x;
  int qt = 31 - (int)blockIdx.y;                  // heavy first
  int b = bh >> 4, h = bh & 15;
  const u16* qp = qb + (size_t)b * 2048 * 1024 + h * 64;
  const u16* kp = kb + (size_t)b * 2048 * 1024 + h * 64;
  const u16* vp = vT + (size_t)bh * 64 * 2048;
  int tid = threadIdx.x, lane = tid & 63, wv = tid >> 6;
  int quad = lane >> 4, l16 = lane & 15;
  int lr8 = lane >> 3, lc8 = (lane & 7) * 8;
  int MR = wv * 16;
  int nkt = qt + 1;
  // prologue: stage Q tile + K/V tile 0 -> buf 0
  #pragma unroll
  for (int t = 0; t < 2; ++t) {
    int idx = wv * 2 + t;
    async16(qp + (size_t)(qt * 64 + idx * 8 + lr8) * 1024 + lc8, &Qs[idx * 512]);
    async16(kp + (size_t)(idx * 8 + lr8) * 1024 + lc8, &Ks[0][idx * 512]);
    async16(vp + (size_t)(idx * 8 + lr8) * 2048 + lc8, &Vts[0][idx * 512]);
  }
  f32x4 zero = {0.f, 0.f, 0.f, 0.f};
  f32x4 oacc[4];
  float ssqr[4] = {0.f, 0.f, 0.f, 0.f};
  #pragma unroll
  for (int dn = 0; dn < 4; ++dn) oacc[dn] = zero;
  for (int kt = 0, cur = 0; kt < nkt; ++kt, cur ^= 1) {
    __syncthreads();                              // staging(kt) complete; buf^1 reads done
    if (kt + 1 < nkt) {
      #pragma unroll
      for (int t = 0; t < 2; ++t) {               // stage kt+1; overlaps full compute below
        int idx = wv * 2 + t;
        async16(kp + (size_t)((kt + 1) * 64 + idx * 8 + lr8) * 1024 + lc8, &Ks[cur ^ 1][idx * 512]);
        async16(vp + (size_t)(idx * 8 + lr8) * 2048 + (kt + 1) * 64 + lc8, &Vts[cur ^ 1][idx * 512]);
      }
    }
    // S = QK^T/8, mask (diagonal tile only), gelu -> Sg (own rows) + ssq
    bf16x8 a0 = *(const bf16x8*)&Qs[(MR + l16) * 64 + quad * 8];
    bf16x8 a1 = *(const bf16x8*)&Qs[(MR + l16) * 64 + 32 + quad * 8];
    bool dg = (kt == qt);
    #pragma unroll
    for (int sn = 0; sn < 4; ++sn) {
      bf16x8 b0 = *(const bf16x8*)&Ks[cur][(sn * 16 + l16) * 64 + quad * 8];
      bf16x8 b1 = *(const bf16x8*)&Ks[cur][(sn * 16 + l16) * 64 + 32 + quad * 8];
      f32x4 s = zero;
      s = __builtin_amdgcn_mfma_f32_16x16x32_bf16(a0, b0, s, 0, 0, 0);
      s = __builtin_amdgcn_mfma_f32_16x16x32_bf16(a1, b1, s, 0, 0, 0);
      int srow = MR + quad * 4;
      int kcol = sn * 16 + l16;
      #pragma unroll
      for (int reg = 0; reg < 4; ++reg) {
        float gl = gelu_f(s[reg] * 0.125f);
        if (dg && kcol > srow + reg) gl = 0.f;
        ssqr[reg] += gl * gl;
        Sg[(srow + reg) * 72 + kcol] = f2b(gl);
      }
    }
    // O += P.V (same-wave Sg rows; compiler inserts lgkmcnt waits)
    bf16x8 p0 = *(const bf16x8*)&Sg[(MR + l16) * 72 + quad * 8];
    bf16x8 p1 = *(const bf16x8*)&Sg[(MR + l16) * 72 + 32 + quad * 8];
    #pragma unroll
    for (int dn = 0; dn < 4; ++dn) {
      bf16x8 v0 = *(const bf16x8*)&Vts[cur][(dn * 16 + l16) * 64 + quad * 8];
      bf16x8 v1 = *(const bf16x8*)&Vts[cur][(dn * 16 + l16) * 64 + 32 + quad * 8];
      oacc[dn] = __builtin_amdgcn_mfma_f32_16x16x32_bf16(p0, v0, oacc[dn], 0, 0, 0);
      oacc[dn] = __builtin_amdgcn_mfma_f32_16x16x32_bf16(p1, v1, oacc[dn], 0, 0, 0);
    }
  }
  float sc[4];
  #pragma unroll
  for (int reg = 0; reg < 4; ++reg) {
    float s = ssqr[reg];
    s += __shfl_xor(s, 1); s += __shfl_xor(s, 2);
    s += __shfl_xor(s, 4); s += __shfl_xor(s, 8);
    sc[reg] = 45.254834f * rsqrtf(s);             // sqrt(2048/ssq)
  }
  #pragma unroll
  for (int dn = 0; dn < 4; ++dn)
    #pragma unroll
    for (int reg = 0; reg < 4; ++reg) {
      int row = qt * 64 + MR + quad * 4 + reg;
      int col = h * 64 + dn * 16 + l16;
      ob[(size_t)(b * 2048 + row) * 1024 + col] = f2b(oacc[dn][reg] * sc[reg]);
    }
}

// ---------------- finalize: out = x1 + 64*rsqrt(ssq)[row] * (p0+p1) ----------------
__global__ __launch_bounds__(256) void fin_kernel(
    const float* __restrict__ p0, const float* __restrict__ p1,
    const float* __restrict__ x1, const float* __restrict__ ssqf,
    float* __restrict__ out) {
  int row = blockIdx.x, t = threadIdx.x;
  float s = 64.0f * rsqrtf(ssqf[row]);
  size_t base = (size_t)row * 1024 + t * 4;
  float4 a = *(const float4*)(p0 + base);
  float4 b = *(const float4*)(p1 + base);
  float4 r = *(const float4*)(x1 + base);
  float4 o;
  o.x = r.x + s * (a.x + b.x); o.y = r.y + s * (a.y + b.y);
  o.z = r.z + s * (a.z + b.z); o.w = r.w + s * (a.w + b.w);
  *(float4*)(out + base) = o;
}

extern "C" void kernel_launch(void* const* d_in, const int* in_sizes, int n_in,
                              void* d_out, int out_size, void* d_ws, size_t ws_size,
                              hipStream_t stream) {
  const float* x    = (const float*)d_in[0];
  const float* ln1w = (const float*)d_in[1];
  const float* ln1b = (const float*)d_in[2];
  const float* ln2w = (const float*)d_in[3];
  const float* ln2b = (const float*)d_in[4];
  const float* qk   = (const float*)d_in[5];
  const float* qv   = (const float*)d_in[6];
  const float* kk   = (const float*)d_in[7];
  const float* kv   = (const float*)d_in[8];
  const float* vk   = (const float*)d_in[9];
  const float* vv   = (const float*)d_in[10];
  const float* pk   = (const float*)d_in[11];
  const float* pv   = (const float*)d_in[12];
  const float* fk   = (const float*)d_in[13];
  const float* fv   = (const float*)d_in[14];
  float* out = (float*)d_out;

  const size_t M1 = 1048576;
  u16* w = (u16*)d_ws;
  u16* wkeys  = w;                  // 0..3M   (qk,kk,vk)   | later p0 covers 0..8M
  u16* wpk    = w + 3 * M1;
  u16* wfk    = w + 4 * M1;         // 4M..8M
  u16* wvalsT = w + 8 * M1;         // 8..11M  (qvT,kvT,vvT)
  u16* wpvT   = w + 11 * M1;
  u16* wfvT   = w + 12 * M1;        // 12..16M
  u16* xn     = w + 16 * M1;        // 16..20M
  u16* gq     = w + 20 * M1;        // qkv ghat z-stride 4M (20..32M); later ob/gp/gf
  u16* ob     = w + 20 * M1;
  u16* gp     = w + 24 * M1;
  u16* gf     = w + 20 * M1;        // ffn ghat 20..36M
  u16* qb     = w + 36 * M1;        // 36..40M  | later p1 covers 36..44M
  u16* kb     = w + 40 * M1;
  u16* vb     = w + 44 * M1;
  u16* vT     = w + 48 * M1;        // 48..52M (ssq overlays its head; vT written after qkv)
  float* ssq_qkv  = (float*)(w + 48 * M1);   // 3*4096 f
  float* ssq_proj = ssq_qkv + 12288;         // 4096 f
  float* ssq_ffn  = ssq_qkv + 16384;         // 4096 f
  float* x1 = (float*)(w + 52 * M1);         // 52..60M (4M f32)
  float* p0 = (float*)w;                     // ffn partial z=0 (weights dead by then)
  float* p1 = (float*)(w + 36 * M1);         // ffn partial z=1 (qb/kb dead)

  dim3 blk(256);
  zero_kernel<<<80, blk, 0, stream>>>(ssq_qkv, 20480);
  cvt4_kernel<<<dim3(1024, 4), blk, 0, stream>>>(qk, kk, vk, pk, wkeys, 262144);
  cvt_kernel<<<4096, blk, 0, stream>>>(fk, wfk, 1048576);
  cvtT4_kernel<<<dim3(32, 32, 4), blk, 0, stream>>>(qv, kv, vv, pv, wvalsT);
  cvtT_kernel<<<dim3(32, 128), blk, 0, stream>>>(fv, wfvT, 4096, 1024);

  ln_kernel<<<1024, blk, 0, stream>>>(x, ln1w, ln1b, xn);
  gemm_key<128><<<dim3(8, 32, 3), blk, 0, stream>>>(
      xn, 0, wkeys, M1, gq, 4 * M1, ssq_qkv, 4096, 1024, 1024, 32.0f);
  gemm_val<128, 0><<<dim3(8, 32, 3), blk, 0, stream>>>(
      gq, 4 * M1, wvalsT, M1, qb, 4 * M1, ssq_qkv, 4096, 1024, 1024, 0, 1024, 32.0f, nullptr);

  rotary_kernel<<<256, blk, 0, stream>>>(qb, kb);
  vt_kernel<<<dim3(32, 32), blk, 0, stream>>>(vb, vT);
  attn_kernel<<<dim3(32, 32), blk, 0, stream>>>(qb, kb, vT, ob);
  zero_kernel<<<32, blk, 0, stream>>>(ssq_proj, 8192);   // vT head dead after attn

  gemm_key<64><<<dim3(8, 64, 1), blk, 0, stream>>>(
      ob, 0, wpk, 0, gp, 0, ssq_proj, 0, 1024, 1024, 32.0f);
  gemm_val<64, 1><<<dim3(8, 64, 1), blk, 0, stream>>>(
      gp, 0, wpvT, 0, x1, 0, ssq_proj, 0, 1024, 1024, 0, 1024, 32.0f, x);

  ln_kernel<<<1024, blk, 0, stream>>>(x1, ln2w, ln2b, xn);
  gemm_key<128><<<dim3(32, 32, 1), blk, 0, stream>>>(
      xn, 0, wfk, 0, gf, 0, ssq_ffn, 0, 4096, 1024, 32.0f);
  gemm_val<128, 2><<<dim3(8, 32, 2), blk, 0, stream>>>(
      gf, 0, wfvT, 0, p0, 18 * M1, ssq_ffn, 0, 1024, 4096, 2048, 2048, 0.0f, nullptr);
  fin_kernel<<<4096, blk, 0, stream>>>(p0, p1, x1, ssq_ffn, out);
}

// Round 6
// 470.533 us; speedup vs baseline: 2.1461x; 1.0349x over previous
//
#include <hip/hip_runtime.h>

typedef __bf16 bf16x8 __attribute__((ext_vector_type(8)));
typedef float f32x4 __attribute__((ext_vector_type(4)));
typedef unsigned short u16;

__device__ __forceinline__ float b2f(u16 u) {
  union { unsigned int i; float f; } v; v.i = ((unsigned int)u) << 16; return v.f;
}
__device__ __forceinline__ u16 f2b(float f) {
  union { float f; unsigned int i; } v; v.f = f;
  unsigned int x = v.i;
  x += 0x7fffu + ((x >> 16) & 1u);   // round-to-nearest-even
  return (u16)(x >> 16);
}
// fast tanh-gelu (validated R4/R5: absmax 0.047)
__device__ __forceinline__ float gelu_f(float x) {
  float x2 = x * x;
  float p = x * (1.5957691216f + 0.0713548162f * x2);
  float e = __expf(p);
  float r = __builtin_amdgcn_rcpf(1.0f + e);
  return x - x * r;
}
__device__ __forceinline__ void async16(const u16* g, u16* l) {
  __builtin_amdgcn_global_load_lds(
      (const __attribute__((address_space(1))) void*)g,
      (__attribute__((address_space(3))) void*)l, 16, 0, 0);
}
// XCD-aware supertile swizzle: flat%8 = XCD (m09 round-robin). Each XCD owns a
// contiguous band of gy/8 A-row-tiles (L2-resident) and streams B tiles; bmi
// cycles fastest so concurrent blocks on one XCD share the same hot B-tile.
__device__ __forceinline__ void swz(int& bn, int& bm, int& bz) {
  int gx = (int)gridDim.x, gy = (int)gridDim.y;
  int flat = (int)(blockIdx.x + gridDim.x * (blockIdx.y + gridDim.y * blockIdx.z));
  int seq = flat >> 3;
  int nbm = gy >> 3;
  bm = (flat & 7) * nbm + seq % nbm;
  int rest = seq / nbm;
  bn = rest % gx;
  bz = rest / gx;
}

union U4 { uint4 u; u16 s[8]; };

// ---------------- zero fp32 ----------------
__global__ __launch_bounds__(256) void zero_kernel(float* __restrict__ p, int n) {
  int i = blockIdx.x * 256 + threadIdx.x;
  if (i < n) p[i] = 0.f;
}

// ---------------- fp32 -> bf16 convert: all 5 K-major weights in one launch ----------------
// z=0..3 -> qk,kk,vk,pk (1M elems each); z=4..7 -> fk quarters. out = w + z*1M.
__global__ __launch_bounds__(256) void cvt8_kernel(
    const float* __restrict__ qk, const float* __restrict__ kk,
    const float* __restrict__ vk, const float* __restrict__ pk,
    const float* __restrict__ fk, u16* __restrict__ w) {
  int z = blockIdx.y;
  const float* in = (z == 0) ? qk : (z == 1) ? kk : (z == 2) ? vk : (z == 3) ? pk
                    : fk + (size_t)(z - 4) * 4194304 / 4 * 4;  // (z-4)*1048576 f4 = *4194304 floats/4
  if (z >= 4) in = fk + (size_t)(z - 4) * 1048576 * 4 / 4;     // keep simple below
  // (clean recompute to avoid confusion)
  in = (z == 0) ? qk : (z == 1) ? kk : (z == 2) ? vk : (z == 3) ? pk
       : fk + (size_t)(z - 4) * 1048576;                        // 1048576 float4-groups*4? no:
  // fk has 4M floats = 1M float4; quarter = 262144 float4 = 1048576 floats.
  u16* o = w + (size_t)z * 1048576;
  int i = blockIdx.x * 256 + threadIdx.x;   // i < 262144 float4s
  float4 f = ((const float4*)in)[i];
  ushort4 s;
  s.x = f2b(f.x); s.y = f2b(f.y); s.z = f2b(f.z); s.w = f2b(f.w);
  ((ushort4*)o)[i] = s;
}

// ---------------- fp32 [R,Cn] -> bf16 transposed [Cn,R] ----------------
__global__ __launch_bounds__(256) void cvtT_kernel(const float* __restrict__ in,
                                                   u16* __restrict__ out, int R, int Cn) {
  __shared__ float t[32][33];
  int bc = blockIdx.x, br = blockIdx.y;
  int tid = threadIdx.x;
  int r = tid >> 5, c = tid & 31;
  #pragma unroll
  for (int i = 0; i < 4; ++i)
    t[r + i * 8][c] = in[(size_t)(br * 32 + r + i * 8) * Cn + bc * 32 + c];
  __syncthreads();
  #pragma unroll
  for (int i = 0; i < 4; ++i)
    out[(size_t)(bc * 32 + r + i * 8) * R + br * 32 + c] = f2b(t[c][r + i * 8]);
}
__global__ __launch_bounds__(256) void cvtT4_kernel(
    const float* __restrict__ a, const float* __restrict__ b,
    const float* __restrict__ c, const float* __restrict__ d,
    u16* __restrict__ out) {
  __shared__ float t[32][33];
  int z = blockIdx.z;
  const float* in = (z == 0) ? a : (z == 1) ? b : (z == 2) ? c : d;
  u16* o = out + (size_t)z * 1048576;
  int bc = blockIdx.x, br = blockIdx.y;
  int tid = threadIdx.x;
  int r = tid >> 5, cc = tid & 31;
  #pragma unroll
  for (int i = 0; i < 4; ++i)
    t[r + i * 8][cc] = in[(size_t)(br * 32 + r + i * 8) * 1024 + bc * 32 + cc];
  __syncthreads();
  #pragma unroll
  for (int i = 0; i < 4; ++i)
    o[(size_t)(bc * 32 + r + i * 8) * 1024 + br * 32 + cc] = f2b(t[cc][r + i * 8]);
}

// ---------------- LayerNorm: wave-per-row, shuffle-only ----------------
__global__ __launch_bounds__(256) void ln_kernel(const float* __restrict__ x,
    const float* __restrict__ w, const float* __restrict__ b, u16* __restrict__ out) {
  int wv = threadIdx.x >> 6, lane = threadIdx.x & 63;
  int row = blockIdx.x * 4 + wv;
  const float* xr = x + (size_t)row * 1024;
  float4 v[4];
  float s = 0.f, s2 = 0.f;
  #pragma unroll
  for (int i = 0; i < 4; ++i) {
    v[i] = ((const float4*)xr)[lane + 64 * i];
    s += v[i].x + v[i].y + v[i].z + v[i].w;
    s2 += v[i].x * v[i].x + v[i].y * v[i].y + v[i].z * v[i].z + v[i].w * v[i].w;
  }
  #pragma unroll
  for (int m = 1; m < 64; m <<= 1) { s += __shfl_xor(s, m); s2 += __shfl_xor(s2, m); }
  float mu = s * (1.0f / 1024.0f);
  float inv = rsqrtf(s2 * (1.0f / 1024.0f) - mu * mu + 1e-5f);
  u16* orow = out + (size_t)row * 1024;
  #pragma unroll
  for (int i = 0; i < 4; ++i) {
    int c = (lane + 64 * i) * 4;
    ushort4 o;
    o.x = f2b((v[i].x - mu) * inv * w[c]     + b[c]);
    o.y = f2b((v[i].y - mu) * inv * w[c + 1] + b[c + 1]);
    o.z = f2b((v[i].z - mu) * inv * w[c + 2] + b[c + 2]);
    o.w = f2b((v[i].w - mu) * inv * w[c + 3] + b[c + 3]);
    ((ushort4*)orow)[lane + 64 * i] = o;
  }
}

// ---------------- key-GEMM (1-barrier dbuf, XCD swizzle) ----------------
template <int TM>
__global__ __launch_bounds__(256) void gemm_key(
    const u16* __restrict__ A, size_t sAz,
    const u16* __restrict__ B, size_t sBz,
    u16* __restrict__ C, size_t sCz,
    float* __restrict__ ssqb, size_t sSz,
    int N, int K, float alpha) {
  constexpr int AI = TM / 32;
  __shared__ __align__(16) u16 As[2][TM * 32];
  __shared__ __align__(16) u16 Bs[2][128 * 32];
  int bn, bm, bz;
  swz(bn, bm, bz);
  const u16* Ab = A + (size_t)bz * sAz + (size_t)bm * TM * K;
  const u16* Bb = B + (size_t)bz * sBz + (size_t)bn * 128 * K;
  int tid = threadIdx.x, lane = tid & 63, wv = tid >> 6;
  int quad = lane >> 4, l16 = lane & 15;
  int lr = lane >> 2, lc = (lane & 3) * 8;
  int wm = wv >> 1, wn = wv & 1;
  int RB = wm * (TM / 2), CB = wn * 64;
  f32x4 zero = {0.f, 0.f, 0.f, 0.f};
  f32x4 acc[AI][4];
  #pragma unroll
  for (int i = 0; i < AI; ++i)
    #pragma unroll
    for (int j = 0; j < 4; ++j) acc[i][j] = zero;
  #pragma unroll
  for (int t = 0; t < TM / 64; ++t) {
    int ia = wv * (TM / 64) + t;
    async16(Ab + (size_t)(ia * 16 + lr) * K + lc, &As[0][ia * 512]);
  }
  #pragma unroll
  for (int t = 0; t < 2; ++t) {
    int ib = wv * 2 + t;
    async16(Bb + (size_t)(ib * 16 + lr) * K + lc, &Bs[0][ib * 512]);
  }
  for (int k0 = 0, cur = 0; k0 < K; k0 += 32, cur ^= 1) {
    __syncthreads();
    if (k0 + 32 < K) {
      #pragma unroll
      for (int t = 0; t < TM / 64; ++t) {
        int ia = wv * (TM / 64) + t;
        async16(Ab + (size_t)(ia * 16 + lr) * K + k0 + 32 + lc, &As[cur ^ 1][ia * 512]);
      }
      #pragma unroll
      for (int t = 0; t < 2; ++t) {
        int ib = wv * 2 + t;
        async16(Bb + (size_t)(ib * 16 + lr) * K + k0 + 32 + lc, &Bs[cur ^ 1][ib * 512]);
      }
    }
    bf16x8 af[AI], bf[4];
    #pragma unroll
    for (int i = 0; i < AI; ++i)
      af[i] = *(const bf16x8*)&As[cur][(RB + i * 16 + l16) * 32 + quad * 8];
    #pragma unroll
    for (int j = 0; j < 4; ++j)
      bf[j] = *(const bf16x8*)&Bs[cur][(CB + j * 16 + l16) * 32 + quad * 8];
    #pragma unroll
    for (int i = 0; i < AI; ++i)
      #pragma unroll
      for (int j = 0; j < 4; ++j)
        acc[i][j] = __builtin_amdgcn_mfma_f32_16x16x32_bf16(af[i], bf[j], acc[i][j], 0, 0, 0);
  }
  #pragma unroll
  for (int i = 0; i < AI; ++i) {
    int rbase = bm * TM + RB + i * 16 + quad * 4;
    float srow[4] = {0.f, 0.f, 0.f, 0.f};
    #pragma unroll
    for (int j = 0; j < 4; ++j) {
      int c = bn * 128 + CB + j * 16 + l16;
      #pragma unroll
      for (int reg = 0; reg < 4; ++reg) {
        float g = gelu_f(acc[i][j][reg] * alpha);
        srow[reg] += g * g;
        C[(size_t)bz * sCz + (size_t)(rbase + reg) * N + c] = f2b(g);
      }
    }
    #pragma unroll
    for (int reg = 0; reg < 4; ++reg) {
      float s = srow[reg];
      s += __shfl_xor(s, 1); s += __shfl_xor(s, 2);
      s += __shfl_xor(s, 4); s += __shfl_xor(s, 8);
      if (l16 == 0) atomicAdd(&ssqb[bz * sSz + rbase + reg], s);
    }
  }
}

// ---------------- val-GEMM (1-barrier dbuf, XCD swizzle) ----------------
// MODE 0: bf16 store, *scale ; 1: f32 store, *scale + res ; 2: f32 raw partial (split-K)
template <int TM, int MODE>
__global__ __launch_bounds__(256) void gemm_val(
    const u16* __restrict__ A, size_t sAz,
    const u16* __restrict__ B, size_t sBz,
    void* __restrict__ C, size_t sCz,
    const float* __restrict__ ssqb, size_t sSz,
    int N, int K, int kzs, int klen, float sqrtP, const float* __restrict__ res) {
  constexpr int AI = TM / 32;
  __shared__ __align__(16) u16 As[2][TM * 32];
  __shared__ __align__(16) u16 Bs[2][128 * 32];
  int bn, bm, bz;
  swz(bn, bm, bz);
  const u16* Ab = A + (size_t)bz * sAz + (size_t)bm * TM * K;
  const u16* Bb = B + (size_t)bz * sBz + (size_t)bn * 128 * K;
  int tid = threadIdx.x, lane = tid & 63, wv = tid >> 6;
  int quad = lane >> 4, l16 = lane & 15;
  int lr = lane >> 2, lc = (lane & 3) * 8;
  int wm = wv >> 1, wn = wv & 1;
  int RB = wm * (TM / 2), CB = wn * 64;
  f32x4 zero = {0.f, 0.f, 0.f, 0.f};
  f32x4 acc[AI][4];
  #pragma unroll
  for (int i = 0; i < AI; ++i)
    #pragma unroll
    for (int j = 0; j < 4; ++j) acc[i][j] = zero;
  int kb0 = bz * kzs;
  #pragma unroll
  for (int t = 0; t < TM / 64; ++t) {
    int ia = wv * (TM / 64) + t;
    async16(Ab + (size_t)(ia * 16 + lr) * K + kb0 + lc, &As[0][ia * 512]);
  }
  #pragma unroll
  for (int t = 0; t < 2; ++t) {
    int ib = wv * 2 + t;
    async16(Bb + (size_t)(ib * 16 + lr) * K + kb0 + lc, &Bs[0][ib * 512]);
  }
  for (int k0 = kb0, cur = 0; k0 < kb0 + klen; k0 += 32, cur ^= 1) {
    __syncthreads();
    if (k0 + 32 < kb0 + klen) {
      #pragma unroll
      for (int t = 0; t < TM / 64; ++t) {
        int ia = wv * (TM / 64) + t;
        async16(Ab + (size_t)(ia * 16 + lr) * K + k0 + 32 + lc, &As[cur ^ 1][ia * 512]);
      }
      #pragma unroll
      for (int t = 0; t < 2; ++t) {
        int ib = wv * 2 + t;
        async16(Bb + (size_t)(ib * 16 + lr) * K + k0 + 32 + lc, &Bs[cur ^ 1][ib * 512]);
      }
    }
    bf16x8 af[AI], bf[4];
    #pragma unroll
    for (int i = 0; i < AI; ++i)
      af[i] = *(const bf16x8*)&As[cur][(RB + i * 16 + l16) * 32 + quad * 8];
    #pragma unroll
    for (int j = 0; j < 4; ++j)
      bf[j] = *(const bf16x8*)&Bs[cur][(CB + j * 16 + l16) * 32 + quad * 8];
    #pragma unroll
    for (int i = 0; i < AI; ++i)
      #pragma unroll
      for (int j = 0; j < 4; ++j)
        acc[i][j] = __builtin_amdgcn_mfma_f32_16x16x32_bf16(af[i], bf[j], acc[i][j], 0, 0, 0);
  }
  #pragma unroll
  for (int i = 0; i < AI; ++i) {
    int rbase = bm * TM + RB + i * 16 + quad * 4;
    float sc[4];
    if (MODE < 2) {
      #pragma unroll
      for (int reg = 0; reg < 4; ++reg)
        sc[reg] = sqrtP * rsqrtf(ssqb[bz * sSz + rbase + reg]);
    }
    #pragma unroll
    for (int j = 0; j < 4; ++j) {
      int c = bn * 128 + CB + j * 16 + l16;
      #pragma unroll
      for (int reg = 0; reg < 4; ++reg) {
        float v = acc[i][j][reg];
        size_t idx = (size_t)(rbase + reg) * N + c;
        if (MODE == 0) {
          ((u16*)C)[(size_t)bz * sCz + idx] = f2b(v * sc[reg]);
        } else if (MODE == 1) {
          ((float*)C)[idx] = v * sc[reg] + res[idx];
        } else {
          ((float*)C)[(size_t)bz * sCz + idx] = v;
        }
      }
    }
  }
}

// ---------------- rotary (in place, bf16) on first 16 dims of each head ----------------
__global__ __launch_bounds__(256) void rotary_kernel(u16* __restrict__ qb, u16* __restrict__ kb) {
  const float F[8] = {1.f, 0.31622776601683794f, 0.1f, 0.03162277660168379f,
                      0.01f, 0.0031622776601683794f, 0.001f, 0.00031622776601683794f};
  int t = blockIdx.x * 256 + threadIdx.x;
  int m = t >> 4;
  int h = t & 15;
  int s = m & 2047;
  u16* qp = qb + (size_t)m * 1024 + h * 64;
  u16* kp = kb + (size_t)m * 1024 + h * 64;
  float q[16], k[16];
  #pragma unroll
  for (int d = 0; d < 16; ++d) { q[d] = b2f(qp[d]); k[d] = b2f(kp[d]); }
  #pragma unroll
  for (int i = 0; i < 8; ++i) {
    float ang = (float)s * F[i];
    float c = cosf(ang), sn = sinf(ang);
    qp[i]     = f2b(q[i] * c - q[i + 8] * sn);
    qp[i + 8] = f2b(q[i + 8] * c + q[i] * sn);
    kp[i]     = f2b(k[i] * c - k[i + 8] * sn);
    kp[i + 8] = f2b(k[i + 8] * c + k[i] * sn);
  }
}

// ---------------- per-head V transpose: vb[b,s,h*64+d] -> vT[bh,d,s] ----------------
__global__ __launch_bounds__(256) void vt_kernel(const u16* __restrict__ vb,
                                                 u16* __restrict__ vT) {
  __shared__ __align__(16) u16 T[64][72];
  int st = blockIdx.x, bh = blockIdx.y;
  int b = bh >> 4, h = bh & 15;
  int tid = threadIdx.x;
  #pragma unroll
  for (int i = 0; i < 2; ++i) {
    int l = tid + 256 * i;
    int s = l >> 3, dc = l & 7;
    *(uint4*)&T[s][dc * 8] =
        *(const uint4*)(vb + (size_t)(b * 2048 + st * 64 + s) * 1024 + h * 64 + dc * 8);
  }
  __syncthreads();
  #pragma unroll
  for (int i = 0; i < 2; ++i) {
    int l = tid + 256 * i;
    int d = l >> 3, scid = l & 7;
    U4 u;
    #pragma unroll
    for (int j = 0; j < 8; ++j) u.s[j] = T[scid * 8 + j][d];
    *(uint4*)(vT + ((size_t)bh * 64 + d) * 2048 + st * 64 + scid * 8) = u.u;
  }
}

// ---------------- fused causal attention + gelu_l2_norm over keys ----------------
// TQ=64 per block; grid (bh, 32) with qt = 31-pr (LPT). flat%8 = bh%8 -> all of a
// head's K/V (512 KB) stays in one XCD's L2. Dbuf K/V LDS, one barrier per kt.
__global__ __launch_bounds__(256) void attn_kernel(
    const u16* __restrict__ qb, const u16* __restrict__ kb,
    const u16* __restrict__ vT, u16* __restrict__ ob) {
  __shared__ __align__(16) u16 Qs[64 * 64];
  __shared__ __align__(16) u16 Ks[2][64 * 64];
  __shared__ __align__(16) u16 Vts[2][64 * 64];
  __shared__ __align__(16) u16 Sg[64 * 72];
  int bh = blockIdx.x;
  int qt = 31 - (int)blockIdx.y;
  int b = bh >> 4, h = bh & 15;
  const u16* qp = qb + (size_t)b * 2048 * 1024 + h * 64;
  const u16* kp = kb + (size_t)b * 2048 * 1024 + h * 64;
  const u16* vp = vT + (size_t)bh * 64 * 2048;
  int tid = threadIdx.x, lane = tid & 63, wv = tid >> 6;
  int quad = lane >> 4, l16 = lane & 15;
  int lr8 = lane >> 3, lc8 = (lane & 7) * 8;
  int MR = wv * 16;
  int nkt = qt + 1;
  #pragma unroll
  for (int t = 0; t < 2; ++t) {
    int idx = wv * 2 + t;
    async16(qp + (size_t)(qt * 64 + idx * 8 + lr8) * 1024 + lc8, &Qs[idx * 512]);
    async16(kp + (size_t)(idx * 8 + lr8) * 1024 + lc8, &Ks[0][idx * 512]);
    async16(vp + (size_t)(idx * 8 + lr8) * 2048 + lc8, &Vts[0][idx * 512]);
  }
  f32x4 zero = {0.f, 0.f, 0.f, 0.f};
  f32x4 oacc[4];
  float ssqr[4] = {0.f, 0.f, 0.f, 0.f};
  #pragma unroll
  for (int dn = 0; dn < 4; ++dn) oacc[dn] = zero;
  for (int kt = 0, cur = 0; kt < nkt; ++kt, cur ^= 1) {
    __syncthreads();
    if (kt + 1 < nkt) {
      #pragma unroll
      for (int t = 0; t < 2; ++t) {
        int idx = wv * 2 + t;
        async16(kp + (size_t)((kt + 1) * 64 + idx * 8 + lr8) * 1024 + lc8, &Ks[cur ^ 1][idx * 512]);
        async16(vp + (size_t)(idx * 8 + lr8) * 2048 + (kt + 1) * 64 + lc8, &Vts[cur ^ 1][idx * 512]);
      }
    }
    bf16x8 a0 = *(const bf16x8*)&Qs[(MR + l16) * 64 + quad * 8];
    bf16x8 a1 = *(const bf16x8*)&Qs[(MR + l16) * 64 + 32 + quad * 8];
    bool dg = (kt == qt);
    #pragma unroll
    for (int sn = 0; sn < 4; ++sn) {
      bf16x8 b0 = *(const bf16x8*)&Ks[cur][(sn * 16 + l16) * 64 + quad * 8];
      bf16x8 b1 = *(const bf16x8*)&Ks[cur][(sn * 16 + l16) * 64 + 32 + quad * 8];
      f32x4 s = zero;
      s = __builtin_amdgcn_mfma_f32_16x16x32_bf16(a0, b0, s, 0, 0, 0);
      s = __builtin_amdgcn_mfma_f32_16x16x32_bf16(a1, b1, s, 0, 0, 0);
      int srow = MR + quad * 4;
      int kcol = sn * 16 + l16;
      #pragma unroll
      for (int reg = 0; reg < 4; ++reg) {
        float gl = gelu_f(s[reg] * 0.125f);
        if (dg && kcol > srow + reg) gl = 0.f;
        ssqr[reg] += gl * gl;
        Sg[(srow + reg) * 72 + kcol] = f2b(gl);
      }
    }
    bf16x8 p0 = *(const bf16x8*)&Sg[(MR + l16) * 72 + quad * 8];
    bf16x8 p1 = *(const bf16x8*)&Sg[(MR + l16) * 72 + 32 + quad * 8];
    #pragma unroll
    for (int dn = 0; dn < 4; ++dn) {
      bf16x8 v0 = *(const bf16x8*)&Vts[cur][(dn * 16 + l16) * 64 + quad * 8];
      bf16x8 v1 = *(const bf16x8*)&Vts[cur][(dn * 16 + l16) * 64 + 32 + quad * 8];
      oacc[dn] = __builtin_amdgcn_mfma_f32_16x16x32_bf16(p0, v0, oacc[dn], 0, 0, 0);
      oacc[dn] = __builtin_amdgcn_mfma_f32_16x16x32_bf16(p1, v1, oacc[dn], 0, 0, 0);
    }
  }
  float sc[4];
  #pragma unroll
  for (int reg = 0; reg < 4; ++reg) {
    float s = ssqr[reg];
    s += __shfl_xor(s, 1); s += __shfl_xor(s, 2);
    s += __shfl_xor(s, 4); s += __shfl_xor(s, 8);
    sc[reg] = 45.254834f * rsqrtf(s);
  }
  #pragma unroll
  for (int dn = 0; dn < 4; ++dn)
    #pragma unroll
    for (int reg = 0; reg < 4; ++reg) {
      int row = qt * 64 + MR + quad * 4 + reg;
      int col = h * 64 + dn * 16 + l16;
      ob[(size_t)(b * 2048 + row) * 1024 + col] = f2b(oacc[dn][reg] * sc[reg]);
    }
}

// ---------------- finalize: out = x1 + 64*rsqrt(ssq)[row] * (p0+p1) ----------------
__global__ __launch_bounds__(256) void fin_kernel(
    const float* __restrict__ p0, const float* __restrict__ p1,
    const float* __restrict__ x1, const float* __restrict__ ssqf,
    float* __restrict__ out) {
  int row = blockIdx.x, t = threadIdx.x;
  float s = 64.0f * rsqrtf(ssqf[row]);
  size_t base = (size_t)row * 1024 + t * 4;
  float4 a = *(const float4*)(p0 + base);
  float4 b = *(const float4*)(p1 + base);
  float4 r = *(const float4*)(x1 + base);
  float4 o;
  o.x = r.x + s * (a.x + b.x); o.y = r.y + s * (a.y + b.y);
  o.z = r.z + s * (a.z + b.z); o.w = r.w + s * (a.w + b.w);
  *(float4*)(out + base) = o;
}

extern "C" void kernel_launch(void* const* d_in, const int* in_sizes, int n_in,
                              void* d_out, int out_size, void* d_ws, size_t ws_size,
                              hipStream_t stream) {
  const float* x    = (const float*)d_in[0];
  const float* ln1w = (const float*)d_in[1];
  const float* ln1b = (const float*)d_in[2];
  const float* ln2w = (const float*)d_in[3];
  const float* ln2b = (const float*)d_in[4];
  const float* qk   = (const float*)d_in[5];
  const float* qv   = (const float*)d_in[6];
  const float* kk   = (const float*)d_in[7];
  const float* kv   = (const float*)d_in[8];
  const float* vk   = (const float*)d_in[9];
  const float* vv   = (const float*)d_in[10];
  const float* pk   = (const float*)d_in[11];
  const float* pv   = (const float*)d_in[12];
  const float* fk   = (const float*)d_in[13];
  const float* fv   = (const float*)d_in[14];
  float* out = (float*)d_out;

  const size_t M1 = 1048576;
  u16* w = (u16*)d_ws;
  u16* wkeys  = w;                  // 0..3M (qk,kk,vk) | later p0 covers 0..8M
  u16* wpk    = w + 3 * M1;
  u16* wfk    = w + 4 * M1;         // 4..8M
  u16* wvalsT = w + 8 * M1;         // 8..11M (qvT,kvT,vvT)
  u16* wpvT   = w + 11 * M1;
  u16* wfvT   = w + 12 * M1;        // 12..16M
  u16* xn     = w + 16 * M1;        // 16..20M
  u16* gq     = w + 20 * M1;        // qkv ghat z-stride 4M (20..32M); later ob/gp/gf
  u16* ob     = w + 20 * M1;
  u16* gp     = w + 24 * M1;
  u16* gf     = w + 20 * M1;        // ffn ghat 20..36M
  u16* qb     = w + 36 * M1;        // 36..40M | later p1 covers 36..44M
  u16* kb     = w + 40 * M1;
  u16* vb     = w + 44 * M1;
  u16* vT     = w + 48 * M1;        // 48..52M (ssq overlays head; re-zeroed after attn)
  float* ssq_qkv  = (float*)(w + 48 * M1);   // 3*4096 f
  float* ssq_proj = ssq_qkv + 12288;         // 4096 f
  float* ssq_ffn  = ssq_qkv + 16384;         // 4096 f
  float* x1 = (float*)(w + 52 * M1);         // 52..60M (4M f32)
  float* p0 = (float*)w;                     // ffn partial z=0 (weights dead)
  float* p1 = (float*)(w + 36 * M1);         // ffn partial z=1 (qb/kb dead)

  dim3 blk(256);
  zero_kernel<<<80, blk, 0, stream>>>(ssq_qkv, 20480);
  cvt8_kernel<<<dim3(1024, 8), blk, 0, stream>>>(qk, kk, vk, pk, fk, w);
  cvtT4_kernel<<<dim3(32, 32, 4), blk, 0, stream>>>(qv, kv, vv, pv, wvalsT);
  cvtT_kernel<<<dim3(32, 128), blk, 0, stream>>>(fv, wfvT, 4096, 1024);

  ln_kernel<<<1024, blk, 0, stream>>>(x, ln1w, ln1b, xn);
  gemm_key<128><<<dim3(8, 32, 3), blk, 0, stream>>>(
      xn, 0, wkeys, M1, gq, 4 * M1, ssq_qkv, 4096, 1024, 1024, 32.0f);
  gemm_val<128, 0><<<dim3(8, 32, 3), blk, 0, stream>>>(
      gq, 4 * M1, wvalsT, M1, qb, 4 * M1, ssq_qkv, 4096, 1024, 1024, 0, 1024, 32.0f, nullptr);

  rotary_kernel<<<256, blk, 0, stream>>>(qb, kb);
  vt_kernel<<<dim3(32, 32), blk, 0, stream>>>(vb, vT);
  attn_kernel<<<dim3(32, 32), blk, 0, stream>>>(qb, kb, vT, ob);
  zero_kernel<<<32, blk, 0, stream>>>(ssq_proj, 8192);   // ssq region clobbered by vT

  gemm_key<64><<<dim3(8, 64, 1), blk, 0, stream>>>(
      ob, 0, wpk, 0, gp, 0, ssq_proj, 0, 1024, 1024, 32.0f);
  gemm_val<64, 1><<<dim3(8, 64, 1), blk, 0, stream>>>(
      gp, 0, wpvT, 0, x1, 0, ssq_proj, 0, 1024, 1024, 0, 1024, 32.0f, x);

  ln_kernel<<<1024, blk, 0, stream>>>(x1, ln2w, ln2b, xn);
  gemm_key<128><<<dim3(32, 32, 1), blk, 0, stream>>>(
      xn, 0, wfk, 0, gf, 0, ssq_ffn, 0, 4096, 1024, 32.0f);
  gemm_val<128, 2><<<dim3(8, 32, 2), blk, 0, stream>>>(
      gf, 0, wfvT, 0, p0, 18 * M1, ssq_ffn, 0, 1024, 4096, 2048, 2048, 0.0f, nullptr);
  fin_kernel<<<4096, blk, 0, stream>>>(p0, p1, x1, ssq_ffn, out);
}

// Round 8
// 445.147 us; speedup vs baseline: 2.2685x; 1.0570x over previous
//
#include <hip/hip_runtime.h>

typedef __bf16 bf16x8 __attribute__((ext_vector_type(8)));
typedef float f32x4 __attribute__((ext_vector_type(4)));
typedef unsigned short u16;

__device__ __forceinline__ float b2f(u16 u) {
  union { unsigned int i; float f; } v; v.i = ((unsigned int)u) << 16; return v.f;
}
__device__ __forceinline__ u16 f2b(float f) {
  union { float f; unsigned int i; } v; v.f = f;
  unsigned int x = v.i;
  x += 0x7fffu + ((x >> 16) & 1u);   // round-to-nearest-even
  return (u16)(x >> 16);
}
// fast tanh-gelu (validated R4-R6: absmax 0.047)
__device__ __forceinline__ float gelu_f(float x) {
  float x2 = x * x;
  float p = x * (1.5957691216f + 0.0713548162f * x2);
  float e = __expf(p);
  float r = __builtin_amdgcn_rcpf(1.0f + e);
  return x - x * r;
}
__device__ __forceinline__ void async16(const u16* g, u16* l) {
  __builtin_amdgcn_global_load_lds(
      (const __attribute__((address_space(1))) void*)g,
      (__attribute__((address_space(3))) void*)l, 16, 0, 0);
}
// XCD-aware supertile swizzle (R6; neutral at worst)
__device__ __forceinline__ void swz(int& bn, int& bm, int& bz) {
  int gx = (int)gridDim.x, gy = (int)gridDim.y;
  int flat = (int)(blockIdx.x + gridDim.x * (blockIdx.y + gridDim.y * blockIdx.z));
  int seq = flat >> 3;
  int nbm = gy >> 3;
  bm = (flat & 7) * nbm + seq % nbm;
  int rest = seq / nbm;
  bn = rest % gx;
  bz = rest / gx;
}

union U4 { uint4 u; u16 s[8]; };
union PF { bf16x8 v; u16 s[8]; };

// ---------------- fp32 -> bf16 convert, all K-major weights + ssq zero, one launch ----------------
// z=0..3: qk,kk,vk,pk ; z=4..7: fk quarters ; z=8: zero 20480 ssq floats.
__global__ __launch_bounds__(256) void cvt9_kernel(
    const float* __restrict__ qk, const float* __restrict__ kk,
    const float* __restrict__ vk, const float* __restrict__ pk,
    const float* __restrict__ fk, u16* __restrict__ w, float* __restrict__ ssqz) {
  int z = blockIdx.y;
  int i = blockIdx.x * 256 + threadIdx.x;
  if (z == 8) {
    if (i < 20480) ssqz[i] = 0.f;
    return;
  }
  const float* in = (z == 0) ? qk : (z == 1) ? kk : (z == 2) ? vk : (z == 3) ? pk
                    : fk + (size_t)(z - 4) * 1048576;
  u16* o = w + (size_t)z * 1048576;
  float4 f = ((const float4*)in)[i];
  ushort4 s;
  s.x = f2b(f.x); s.y = f2b(f.y); s.z = f2b(f.z); s.w = f2b(f.w);
  ((ushort4*)o)[i] = s;
}

// ---------------- fp32 [R,1024] -> bf16 transposed, all val weights, one launch ----------------
__global__ __launch_bounds__(256) void cvtT8_kernel(
    const float* __restrict__ qv, const float* __restrict__ kv,
    const float* __restrict__ vv, const float* __restrict__ pv,
    const float* __restrict__ fv, u16* __restrict__ valsT, u16* __restrict__ fvT) {
  __shared__ float t[32][33];
  int z = blockIdx.z;
  const float* in; u16* o; int Rout, rowoff;
  if (z < 4) {
    in = (z == 0) ? qv : (z == 1) ? kv : (z == 2) ? vv : pv;
    o = valsT + (size_t)z * 1048576; Rout = 1024; rowoff = 0;
  } else {
    in = fv + (size_t)(z - 4) * 1048576;
    o = fvT; Rout = 4096; rowoff = (z - 4) * 1024;
  }
  int bc = blockIdx.x, br = blockIdx.y;
  int tid = threadIdx.x;
  int r = tid >> 5, cc = tid & 31;
  #pragma unroll
  for (int i = 0; i < 4; ++i)
    t[r + i * 8][cc] = in[(size_t)(br * 32 + r + i * 8) * 1024 + bc * 32 + cc];
  __syncthreads();
  #pragma unroll
  for (int i = 0; i < 4; ++i)
    o[(size_t)(bc * 32 + r + i * 8) * Rout + rowoff + br * 32 + cc] = f2b(t[cc][r + i * 8]);
}

// ---------------- LayerNorm: wave-per-row, shuffle-only ----------------
__global__ __launch_bounds__(256) void ln_kernel(const float* __restrict__ x,
    const float* __restrict__ w, const float* __restrict__ b, u16* __restrict__ out) {
  int wv = threadIdx.x >> 6, lane = threadIdx.x & 63;
  int row = blockIdx.x * 4 + wv;
  const float* xr = x + (size_t)row * 1024;
  float4 v[4];
  float s = 0.f, s2 = 0.f;
  #pragma unroll
  for (int i = 0; i < 4; ++i) {
    v[i] = ((const float4*)xr)[lane + 64 * i];
    s += v[i].x + v[i].y + v[i].z + v[i].w;
    s2 += v[i].x * v[i].x + v[i].y * v[i].y + v[i].z * v[i].z + v[i].w * v[i].w;
  }
  #pragma unroll
  for (int m = 1; m < 64; m <<= 1) { s += __shfl_xor(s, m); s2 += __shfl_xor(s2, m); }
  float mu = s * (1.0f / 1024.0f);
  float inv = rsqrtf(s2 * (1.0f / 1024.0f) - mu * mu + 1e-5f);
  u16* orow = out + (size_t)row * 1024;
  #pragma unroll
  for (int i = 0; i < 4; ++i) {
    int c = (lane + 64 * i) * 4;
    ushort4 o;
    o.x = f2b((v[i].x - mu) * inv * w[c]     + b[c]);
    o.y = f2b((v[i].y - mu) * inv * w[c + 1] + b[c + 1]);
    o.z = f2b((v[i].z - mu) * inv * w[c + 2] + b[c + 2]);
    o.w = f2b((v[i].w - mu) * inv * w[c + 3] + b[c + 3]);
    ((ushort4*)orow)[lane + 64 * i] = o;
  }
}

// ---------------- key-GEMM (1-barrier dbuf, XCD swizzle) ----------------
template <int TM>
__global__ __launch_bounds__(256) void gemm_key(
    const u16* __restrict__ A, size_t sAz,
    const u16* __restrict__ B, size_t sBz,
    u16* __restrict__ C, size_t sCz,
    float* __restrict__ ssqb, size_t sSz,
    int N, int K, float alpha) {
  constexpr int AI = TM / 32;
  __shared__ __align__(16) u16 As[2][TM * 32];
  __shared__ __align__(16) u16 Bs[2][128 * 32];
  int bn, bm, bz;
  swz(bn, bm, bz);
  const u16* Ab = A + (size_t)bz * sAz + (size_t)bm * TM * K;
  const u16* Bb = B + (size_t)bz * sBz + (size_t)bn * 128 * K;
  int tid = threadIdx.x, lane = tid & 63, wv = tid >> 6;
  int quad = lane >> 4, l16 = lane & 15;
  int lr = lane >> 2, lc = (lane & 3) * 8;
  int wm = wv >> 1, wn = wv & 1;
  int RB = wm * (TM / 2), CB = wn * 64;
  f32x4 zero = {0.f, 0.f, 0.f, 0.f};
  f32x4 acc[AI][4];
  #pragma unroll
  for (int i = 0; i < AI; ++i)
    #pragma unroll
    for (int j = 0; j < 4; ++j) acc[i][j] = zero;
  #pragma unroll
  for (int t = 0; t < TM / 64; ++t) {
    int ia = wv * (TM / 64) + t;
    async16(Ab + (size_t)(ia * 16 + lr) * K + lc, &As[0][ia * 512]);
  }
  #pragma unroll
  for (int t = 0; t < 2; ++t) {
    int ib = wv * 2 + t;
    async16(Bb + (size_t)(ib * 16 + lr) * K + lc, &Bs[0][ib * 512]);
  }
  for (int k0 = 0, cur = 0; k0 < K; k0 += 32, cur ^= 1) {
    __syncthreads();
    if (k0 + 32 < K) {
      #pragma unroll
      for (int t = 0; t < TM / 64; ++t) {
        int ia = wv * (TM / 64) + t;
        async16(Ab + (size_t)(ia * 16 + lr) * K + k0 + 32 + lc, &As[cur ^ 1][ia * 512]);
      }
      #pragma unroll
      for (int t = 0; t < 2; ++t) {
        int ib = wv * 2 + t;
        async16(Bb + (size_t)(ib * 16 + lr) * K + k0 + 32 + lc, &Bs[cur ^ 1][ib * 512]);
      }
    }
    bf16x8 af[AI], bf[4];
    #pragma unroll
    for (int i = 0; i < AI; ++i)
      af[i] = *(const bf16x8*)&As[cur][(RB + i * 16 + l16) * 32 + quad * 8];
    #pragma unroll
    for (int j = 0; j < 4; ++j)
      bf[j] = *(const bf16x8*)&Bs[cur][(CB + j * 16 + l16) * 32 + quad * 8];
    #pragma unroll
    for (int i = 0; i < AI; ++i)
      #pragma unroll
      for (int j = 0; j < 4; ++j)
        acc[i][j] = __builtin_amdgcn_mfma_f32_16x16x32_bf16(af[i], bf[j], acc[i][j], 0, 0, 0);
  }
  #pragma unroll
  for (int i = 0; i < AI; ++i) {
    int rbase = bm * TM + RB + i * 16 + quad * 4;
    float srow[4] = {0.f, 0.f, 0.f, 0.f};
    #pragma unroll
    for (int j = 0; j < 4; ++j) {
      int c = bn * 128 + CB + j * 16 + l16;
      #pragma unroll
      for (int reg = 0; reg < 4; ++reg) {
        float g = gelu_f(acc[i][j][reg] * alpha);
        srow[reg] += g * g;
        C[(size_t)bz * sCz + (size_t)(rbase + reg) * N + c] = f2b(g);
      }
    }
    #pragma unroll
    for (int reg = 0; reg < 4; ++reg) {
      float s = srow[reg];
      s += __shfl_xor(s, 1); s += __shfl_xor(s, 2);
      s += __shfl_xor(s, 4); s += __shfl_xor(s, 8);
      if (l16 == 0) atomicAdd(&ssqb[bz * sSz + rbase + reg], s);
    }
  }
}

// ---------------- val-GEMM (1-barrier dbuf, XCD swizzle) ----------------
// MODE 0: bf16 store, *scale (ROT: fused rotary for bz<2, head cols 0..15)
// MODE 1: f32 store, *scale + res ; MODE 2: f32 raw partial (split-K)
template <int TM, int MODE, bool ROT>
__global__ __launch_bounds__(256) void gemm_val(
    const u16* __restrict__ A, size_t sAz,
    const u16* __restrict__ B, size_t sBz,
    void* __restrict__ C, size_t sCz,
    const float* __restrict__ ssqb, size_t sSz,
    int N, int K, int kzs, int klen, float sqrtP, const float* __restrict__ res) {
  constexpr int AI = TM / 32;
  __shared__ __align__(16) u16 As[2][TM * 32];
  __shared__ __align__(16) u16 Bs[2][128 * 32];
  int bn, bm, bz;
  swz(bn, bm, bz);
  const u16* Ab = A + (size_t)bz * sAz + (size_t)bm * TM * K;
  const u16* Bb = B + (size_t)bz * sBz + (size_t)bn * 128 * K;
  int tid = threadIdx.x, lane = tid & 63, wv = tid >> 6;
  int quad = lane >> 4, l16 = lane & 15;
  int lr = lane >> 2, lc = (lane & 3) * 8;
  int wm = wv >> 1, wn = wv & 1;
  int RB = wm * (TM / 2), CB = wn * 64;
  f32x4 zero = {0.f, 0.f, 0.f, 0.f};
  f32x4 acc[AI][4];
  #pragma unroll
  for (int i = 0; i < AI; ++i)
    #pragma unroll
    for (int j = 0; j < 4; ++j) acc[i][j] = zero;
  int kb0 = bz * kzs;
  #pragma unroll
  for (int t = 0; t < TM / 64; ++t) {
    int ia = wv * (TM / 64) + t;
    async16(Ab + (size_t)(ia * 16 + lr) * K + kb0 + lc, &As[0][ia * 512]);
  }
  #pragma unroll
  for (int t = 0; t < 2; ++t) {
    int ib = wv * 2 + t;
    async16(Bb + (size_t)(ib * 16 + lr) * K + kb0 + lc, &Bs[0][ib * 512]);
  }
  for (int k0 = kb0, cur = 0; k0 < kb0 + klen; k0 += 32, cur ^= 1) {
    __syncthreads();
    if (k0 + 32 < kb0 + klen) {
      #pragma unroll
      for (int t = 0; t < TM / 64; ++t) {
        int ia = wv * (TM / 64) + t;
        async16(Ab + (size_t)(ia * 16 + lr) * K + k0 + 32 + lc, &As[cur ^ 1][ia * 512]);
      }
      #pragma unroll
      for (int t = 0; t < 2; ++t) {
        int ib = wv * 2 + t;
        async16(Bb + (size_t)(ib * 16 + lr) * K + k0 + 32 + lc, &Bs[cur ^ 1][ib * 512]);
      }
    }
    bf16x8 af[AI], bf[4];
    #pragma unroll
    for (int i = 0; i < AI; ++i)
      af[i] = *(const bf16x8*)&As[cur][(RB + i * 16 + l16) * 32 + quad * 8];
    #pragma unroll
    for (int j = 0; j < 4; ++j)
      bf[j] = *(const bf16x8*)&Bs[cur][(CB + j * 16 + l16) * 32 + quad * 8];
    #pragma unroll
    for (int i = 0; i < AI; ++i)
      #pragma unroll
      for (int j = 0; j < 4; ++j)
        acc[i][j] = __builtin_amdgcn_mfma_f32_16x16x32_bf16(af[i], bf[j], acc[i][j], 0, 0, 0);
  }
  #pragma unroll
  for (int i = 0; i < AI; ++i) {
    int rbase = bm * TM + RB + i * 16 + quad * 4;
    float sc[4];
    if (MODE < 2) {
      #pragma unroll
      for (int reg = 0; reg < 4; ++reg)
        sc[reg] = sqrtP * rsqrtf(ssqb[bz * sSz + rbase + reg]);
    }
    #pragma unroll
    for (int j = 0; j < 4; ++j) {
      int c = bn * 128 + CB + j * 16 + l16;
      #pragma unroll
      for (int reg = 0; reg < 4; ++reg) {
        float v = acc[i][j][reg];
        size_t idx = (size_t)(rbase + reg) * N + c;
        if (MODE == 0) {
          float vs = v * sc[reg];
          if (ROT && j == 0) {   // cols c%64 = l16 < 16: the rotary dims of each head
            float prt = __shfl_xor(vs, 8);
            if (bz < 2) {
              int seq = (rbase + reg) & 2047;
              float fr = exp2f((float)(l16 & 7) * -1.66096404744368f);  // 10000^-(i/8)
              float ang = (float)seq * fr;
              float c_ = __cosf(ang), s_ = __sinf(ang);
              vs = (l16 < 8) ? (vs * c_ - prt * s_) : (vs * c_ + prt * s_);
            }
          }
          ((u16*)C)[(size_t)bz * sCz + idx] = f2b(vs);
        } else if (MODE == 1) {
          ((float*)C)[idx] = v * sc[reg] + res[idx];
        } else {
          ((float*)C)[(size_t)bz * sCz + idx] = v;
        }
      }
    }
  }
}

// ---------------- per-head V transpose + PV-slot permutation ----------------
// vb[b,s,h*64+d] -> vT[bh, d, s'] where within each 32-key block the key order is
// permuted to slot q*8+c*4+r <- orig c*16+q*4+r, matching the 16x16x32 MFMA
// B-operand lane mapping so register-held P (from S^T C-layout) pairs correctly.
__global__ __launch_bounds__(256) void vt_kernel(const u16* __restrict__ vb,
                                                 u16* __restrict__ vT) {
  __shared__ __align__(16) u16 T[64][72];
  int st = blockIdx.x, bh = blockIdx.y;
  int b = bh >> 4, h = bh & 15;
  int tid = threadIdx.x;
  #pragma unroll
  for (int i = 0; i < 2; ++i) {
    int l = tid + 256 * i;
    int s = l >> 3, dc = l & 7;
    *(uint4*)&T[s][dc * 8] =
        *(const uint4*)(vb + (size_t)(b * 2048 + st * 64 + s) * 1024 + h * 64 + dc * 8);
  }
  __syncthreads();
  #pragma unroll
  for (int i = 0; i < 2; ++i) {
    int l = tid + 256 * i;
    int d = l >> 3, scid = l & 7;
    int blk = (scid >> 2) * 32;
    int qq = (scid & 3) * 4;
    U4 u;
    #pragma unroll
    for (int j = 0; j < 8; ++j)
      u.s[j] = T[blk + (j >> 2) * 16 + qq + (j & 3)][d];
    *(uint4*)(vT + ((size_t)bh * 64 + d) * 2048 + st * 64 + scid * 8) = u.u;
  }
}

// ---------------- fused causal attention, register-resident P ----------------
// S^T = K.Q^T (A=K-frag, B=Q-frag) -> C-layout lane holds S[q=l16][k=quad*4+reg].
// gelu'd values packed in-register form a valid A-operand for 16x16x32 PV MFMA
// against the slot-permuted vT (see vt_kernel). No S LDS round-trip.
__global__ __launch_bounds__(256) void attn_kernel(
    const u16* __restrict__ qb, const u16* __restrict__ kb,
    const u16* __restrict__ vT, u16* __restrict__ ob) {
  __shared__ __align__(16) u16 Qs[64 * 64];       // 8 KB
  __shared__ __align__(16) u16 Ks[2][64 * 64];    // 16 KB
  __shared__ __align__(16) u16 Vts[2][64 * 64];   // 16 KB
  int bh = blockIdx.x;
  int qt = 31 - (int)blockIdx.y;                  // LPT: heavy tiles first
  int b = bh >> 4, h = bh & 15;
  const u16* qp = qb + (size_t)b * 2048 * 1024 + h * 64;
  const u16* kp = kb + (size_t)b * 2048 * 1024 + h * 64;
  const u16* vp = vT + (size_t)bh * 64 * 2048;
  int tid = threadIdx.x, lane = tid & 63, wv = tid >> 6;
  int quad = lane >> 4, l16 = lane & 15;
  int lr8 = lane >> 3, lc8 = (lane & 7) * 8;
  int MR = wv * 16;
  int nkt = qt + 1;
  #pragma unroll
  for (int t = 0; t < 2; ++t) {
    int idx = wv * 2 + t;
    async16(qp + (size_t)(qt * 64 + idx * 8 + lr8) * 1024 + lc8, &Qs[idx * 512]);
    async16(kp + (size_t)(idx * 8 + lr8) * 1024 + lc8, &Ks[0][idx * 512]);
    async16(vp + (size_t)(idx * 8 + lr8) * 2048 + lc8, &Vts[0][idx * 512]);
  }
  f32x4 zero = {0.f, 0.f, 0.f, 0.f};
  f32x4 oacc[4];
  #pragma unroll
  for (int dn = 0; dn < 4; ++dn) oacc[dn] = zero;
  float ssql = 0.f;
  bf16x8 bq0 = {}, bq1 = {};
  for (int kt = 0, cur = 0; kt < nkt; ++kt, cur ^= 1) {
    __syncthreads();                              // staging(kt) done; buf^1 reads done
    if (kt == 0) {                                // Q frags once (B-operand: n=q=l16)
      bq0 = *(const bf16x8*)&Qs[(MR + l16) * 64 + quad * 8];
      bq1 = *(const bf16x8*)&Qs[(MR + l16) * 64 + 32 + quad * 8];
    }
    if (kt + 1 < nkt) {
      #pragma unroll
      for (int t = 0; t < 2; ++t) {               // prefetch kt+1, overlaps compute
        int idx = wv * 2 + t;
        async16(kp + (size_t)((kt + 1) * 64 + idx * 8 + lr8) * 1024 + lc8, &Ks[cur ^ 1][idx * 512]);
        async16(vp + (size_t)(idx * 8 + lr8) * 2048 + (kt + 1) * 64 + lc8, &Vts[cur ^ 1][idx * 512]);
      }
    }
    bool dg = (kt == qt);
    #pragma unroll
    for (int kc = 0; kc < 2; ++kc) {              // two 32-key chunks
      PF pf;
      #pragma unroll
      for (int snh = 0; snh < 2; ++snh) {
        int sn = kc * 2 + snh;
        bf16x8 ak0 = *(const bf16x8*)&Ks[cur][(sn * 16 + l16) * 64 + quad * 8];
        bf16x8 ak1 = *(const bf16x8*)&Ks[cur][(sn * 16 + l16) * 64 + 32 + quad * 8];
        f32x4 st = zero;
        st = __builtin_amdgcn_mfma_f32_16x16x32_bf16(ak0, bq0, st, 0, 0, 0);
        st = __builtin_amdgcn_mfma_f32_16x16x32_bf16(ak1, bq1, st, 0, 0, 0);
        #pragma unroll
        for (int r = 0; r < 4; ++r) {
          float gl = gelu_f(st[r] * 0.125f);
          if (dg && (sn * 16 + quad * 4 + r > MR + l16)) gl = 0.f;
          ssql += gl * gl;
          pf.s[snh * 4 + r] = f2b(gl);
        }
      }
      #pragma unroll
      for (int dn = 0; dn < 4; ++dn) {
        bf16x8 bv = *(const bf16x8*)&Vts[cur][(dn * 16 + l16) * 64 + kc * 32 + quad * 8];
        oacc[dn] = __builtin_amdgcn_mfma_f32_16x16x32_bf16(pf.v, bv, oacc[dn], 0, 0, 0);
      }
    }
  }
  // ssq[q=l16]: reduce across quads
  ssql += __shfl_xor(ssql, 16);
  ssql += __shfl_xor(ssql, 32);
  float sc = 45.254834f * rsqrtf(ssql);           // sqrt(2048/ssq), held at lane l16=q
  #pragma unroll
  for (int dn = 0; dn < 4; ++dn)
    #pragma unroll
    for (int r = 0; r < 4; ++r) {
      float scr = __shfl(sc, quad * 4 + r);       // O rows are q=quad*4+reg (C-layout)
      int row = qt * 64 + MR + quad * 4 + r;
      int col = h * 64 + dn * 16 + l16;
      ob[(size_t)(b * 2048 + row) * 1024 + col] = f2b(oacc[dn][r] * scr);
    }
}

// ---------------- finalize: out = x1 + 64*rsqrt(ssq)[row] * (p0+p1) ----------------
__global__ __launch_bounds__(256) void fin_kernel(
    const float* __restrict__ p0, const float* __restrict__ p1,
    const float* __restrict__ x1, const float* __restrict__ ssqf,
    float* __restrict__ out) {
  int row = blockIdx.x, t = threadIdx.x;
  float s = 64.0f * rsqrtf(ssqf[row]);
  size_t base = (size_t)row * 1024 + t * 4;
  float4 a = *(const float4*)(p0 + base);
  float4 b = *(const float4*)(p1 + base);
  float4 r = *(const float4*)(x1 + base);
  float4 o;
  o.x = r.x + s * (a.x + b.x); o.y = r.y + s * (a.y + b.y);
  o.z = r.z + s * (a.z + b.z); o.w = r.w + s * (a.w + b.w);
  *(float4*)(out + base) = o;
}

extern "C" void kernel_launch(void* const* d_in, const int* in_sizes, int n_in,
                              void* d_out, int out_size, void* d_ws, size_t ws_size,
                              hipStream_t stream) {
  const float* x    = (const float*)d_in[0];
  const float* ln1w = (const float*)d_in[1];
  const float* ln1b = (const float*)d_in[2];
  const float* ln2w = (const float*)d_in[3];
  const float* ln2b = (const float*)d_in[4];
  const float* qk   = (const float*)d_in[5];
  const float* qv   = (const float*)d_in[6];
  const float* kk   = (const float*)d_in[7];
  const float* kv   = (const float*)d_in[8];
  const float* vk   = (const float*)d_in[9];
  const float* vv   = (const float*)d_in[10];
  const float* pk   = (const float*)d_in[11];
  const float* pv   = (const float*)d_in[12];
  const float* fk   = (const float*)d_in[13];
  const float* fv   = (const float*)d_in[14];
  float* out = (float*)d_out;

  const size_t M1 = 1048576;
  u16* w = (u16*)d_ws;
  u16* wkeys  = w;                  // 0..3M qk,kk,vk | p0 covers 0..8M at ffn-val
  u16* wpk    = w + 3 * M1;
  u16* wfk    = w + 4 * M1;         // 4..8M
  u16* wvalsT = w + 8 * M1;         // 8..12M qvT,kvT,vvT,pvT
  u16* wpvT   = w + 11 * M1;
  u16* wfvT   = w + 12 * M1;        // 12..16M
  u16* xn     = w + 16 * M1;        // 16..20M
  u16* gq     = w + 20 * M1;        // qkv ghat z-stride 4M: 20,24,28
  u16* ob     = w + 20 * M1;        // attn out (gq z=0 dead)
  u16* vT     = w + 24 * M1;        // permuted V (gq z=1 dead)
  u16* gp     = w + 28 * M1;        // proj ghat (gq z=2 dead)
  u16* gf     = w + 20 * M1;        // ffn ghat 20..36M (ob/vT/gp dead)
  u16* qb     = w + 36 * M1;        // | p1 covers 36..44M at ffn-val
  u16* kb     = w + 40 * M1;
  u16* vb     = w + 44 * M1;
  float* ssq_qkv  = (float*)(w + 48 * M1);   // ssq region, never clobbered
  float* ssq_proj = ssq_qkv + 12288;
  float* ssq_ffn  = ssq_qkv + 16384;
  float* x1 = (float*)(w + 52 * M1);         // 52..60M
  float* p0 = (float*)w;
  float* p1 = (float*)(w + 36 * M1);

  dim3 blk(256);
  cvt9_kernel<<<dim3(1024, 9), blk, 0, stream>>>(qk, kk, vk, pk, fk, w, ssq_qkv);
  cvtT8_kernel<<<dim3(32, 32, 8), blk, 0, stream>>>(qv, kv, vv, pv, fv, wvalsT, wfvT);

  ln_kernel<<<1024, blk, 0, stream>>>(x, ln1w, ln1b, xn);
  gemm_key<128><<<dim3(8, 32, 3), blk, 0, stream>>>(
      xn, 0, wkeys, M1, gq, 4 * M1, ssq_qkv, 4096, 1024, 1024, 32.0f);
  gemm_val<128, 0, true><<<dim3(8, 32, 3), blk, 0, stream>>>(
      gq, 4 * M1, wvalsT, M1, qb, 4 * M1, ssq_qkv, 4096, 1024, 1024, 0, 1024, 32.0f, nullptr);

  vt_kernel<<<dim3(32, 32), blk, 0, stream>>>(vb, vT);
  attn_kernel<<<dim3(32, 32), blk, 0, stream>>>(qb, kb, vT, ob);

  gemm_key<64><<<dim3(8, 64, 1), blk, 0, stream>>>(
      ob, 0, wpk, 0, gp, 0, ssq_proj, 0, 1024, 1024, 32.0f);
  gemm_val<64, 1, false><<<dim3(8, 64, 1), blk, 0, stream>>>(
      gp, 0, wpvT, 0, x1, 0, ssq_proj, 0, 1024, 1024, 0, 1024, 32.0f, x);

  ln_kernel<<<1024, blk, 0, stream>>>(x1, ln2w, ln2b, xn);
  gemm_key<128><<<dim3(32, 32, 1), blk, 0, stream>>>(
      xn, 0, wfk, 0, gf, 0, ssq_ffn, 0, 4096, 1024, 32.0f);
  gemm_val<128, 2, false><<<dim3(8, 32, 2), blk, 0, stream>>>(
      gf, 0, wfvT, 0, p0, 18 * M1, ssq_ffn, 0, 1024, 4096, 2048, 2048, 0.0f, nullptr);
  fin_kernel<<<4096, blk, 0, stream>>>(p0, p1, x1, ssq_ffn, out);
}